// Round 3
// baseline (160.747 us; speedup 1.0000x reference)
//
#include <hip/hip_runtime.h>
#include <cfloat>

// ---- problem constants (fixed by setup_inputs) ----
constexpr int A_TOT = 21504;      // 128^2 + 64^2 + 32^2
constexpr int NB    = 8;
constexpr int NG    = 20;
constexpr int HW_M  = 1 << 20;    // 1024*1024
constexpr int SPLIT = 8;          // chunks per (b,g) row for top-k
constexpr int CHUNK = A_TOT / SPLIT;   // 2688
constexpr int MBLK  = 2048;       // k_mask blocks (256 per batch image)

// ---- workspace layout (float offsets) ----
constexpr size_t OFF_DEC  = 0;
constexpr size_t SZ_DEC   = (size_t)NB * A_TOT * 8;            // 1,376,256
constexpr size_t OFF_IOUS = OFF_DEC + SZ_DEC;
constexpr size_t SZ_GA    = (size_t)NB * NG * A_TOT;           // 3,440,640
constexpr size_t OFF_COST = OFF_IOUS + SZ_GA;
constexpr size_t OFF_THRC = OFF_COST + SZ_GA;                  // NB*NG floats
constexpr size_t OFF_THRI = OFF_THRC + NB * NG;                // NB*NG ints
constexpr size_t OFF_CAND = OFF_THRI + NB * NG;                // NB*A_TOT bytes
constexpr size_t OFF_PM   = OFF_CAND + (NB * A_TOT) / 4;       // 672*4 floats
constexpr size_t OFF_PK   = OFF_PM + 672 * 4;                  // MBLK*10 floats
constexpr size_t OFF_PV   = OFF_PK + (size_t)MBLK * 10;        // part iou vals
constexpr size_t SZ_PART  = (size_t)NB * NG * SPLIT * 10;      // 12,800
constexpr size_t OFF_PC   = OFF_PV + SZ_PART;                  // part costs
constexpr size_t OFF_PI   = OFF_PC + SZ_PART;                  // part idx (int)

__device__ __forceinline__ float sigf(float x) { return 1.f / (1.f + expf(-x)); }
__device__ __forceinline__ float bcef(float x, float y) {
  return fmaxf(x, 0.f) - x * y + log1pf(expf(-fabsf(x)));
}
__device__ __forceinline__ void anchor_geom(int a, int& hw, int& lw, float& st) {
  if (a < 16384)      { hw = a;         lw = 7; st = 8.f;  }
  else if (a < 20480) { hw = a - 16384; lw = 6; st = 16.f; }
  else                { hw = a - 20480; lw = 5; st = 32.f; }
}

// -------- fused decode + cost/iou/cand: per-(b,a) thread loops 20 gts --------
__global__ __launch_bounds__(256) void k_cost(
    const float* __restrict__ p3, const float* __restrict__ p4,
    const float* __restrict__ p5, const float* __restrict__ labels,
    float* __restrict__ dec, float* __restrict__ ious,
    float* __restrict__ cost, unsigned char* __restrict__ cand) {
  __shared__ float gt[NG][5];
  int tid = threadIdx.x, b = blockIdx.y;
  if (tid < NG * 5) ((float*)gt)[tid] = labels[b * NG * 5 + tid];
  __syncthreads();
  int a = blockIdx.x * 256 + tid;

  // ---- inline decode ----
  int hw, lw; float st;
  anchor_geom(a, hw, lw, st);
  const float* src; int HW;
  if (a < 16384)      { src = p3; HW = 16384; }
  else if (a < 20480) { src = p4; HW = 4096;  }
  else                { src = p5; HW = 1024;  }
  int x = hw & ((1 << lw) - 1), y = hw >> lw;
  const float* c0 = src + (size_t)b * 8 * HW + hw;
  float o0 = c0[0];
  float o1 = c0[(size_t)HW];
  float o2 = c0[(size_t)2 * HW];
  float o3 = c0[(size_t)3 * HW];
  float o4 = c0[(size_t)4 * HW];
  float o5 = c0[(size_t)5 * HW];
  float o6 = c0[(size_t)6 * HW];
  float o7 = c0[(size_t)7 * HW];
  float px = (o0 + (float)x) * st, py = (o1 + (float)y) * st;
  float pw = expf(o2) * st,        ph = expf(o3) * st;
  {
    float4* dst = (float4*)(dec + ((size_t)b * A_TOT + a) * 8);
    dst[0] = make_float4(px, py, pw, ph);
    dst[1] = make_float4(o4, o5, o6, o7);
  }

  float xc = ((float)x + 0.5f) * st, yc = ((float)y + 0.5f) * st;

  // per-anchor class-cost pieces: cls_cost(g) = -(cc[cg] + S)
  float so = sigf(o4);
  float cc0, cc1, cc2, S;
  {
    float q0 = sqrtf(sigf(o5) * so);
    float q1 = sqrtf(sigf(o6) * so);
    float q2 = sqrtf(sigf(o7) * so);
    float lg0 = logf(q0 + 1e-8f), lg1 = logf(q1 + 1e-8f), lg2 = logf(q2 + 1e-8f);
    float m0 = logf(1.f - q0 + 1e-8f), m1 = logf(1.f - q1 + 1e-8f), m2 = logf(1.f - q2 + 1e-8f);
    S = m0 + m1 + m2;
    cc0 = lg0 - m0; cc1 = lg1 - m1; cc2 = lg2 - m2;
  }

  float iouv[NG];
  unsigned bothMask = 0;
  bool anyBox = false, anyCtr = false;
  float hpw = pw * 0.5f, hph = ph * 0.5f;
  float plx = px - hpw, prx = px + hpw, pty = py - hph, pby = py + hph;
  float parea = pw * ph;
  float r = 2.5f * st;

#pragma unroll
  for (int g = 0; g < NG; ++g) {
    float gx = gt[g][0], gy = gt[g][1], gw = gt[g][2], gh = gt[g][3];
    float hgw = gw * 0.5f, hgh = gh * 0.5f;
    float glx = gx - hgw, grx = gx + hgw, gty = gy - hgh, gby = gy + hgh;
    bool ib = (xc > glx) && (xc < grx) && (yc > gty) && (yc < gby);
    bool ic = (xc > gx - r) && (xc < gx + r) && (yc > gy - r) && (yc < gy + r);
    anyBox |= ib; anyCtr |= ic;
    if (ib && ic) bothMask |= (1u << g);
    float tlx = fmaxf(glx, plx), brx = fminf(grx, prx);
    float tly = fmaxf(gty, pty), bry = fminf(gby, pby);
    float en = ((tlx < brx) && (tly < bry)) ? 1.f : 0.f;
    float ai = (brx - tlx) * (bry - tly) * en;
    float au = gw * gh + parea - ai;
    iouv[g] = ai / (au + 1e-16f);
  }
  bool cd = anyBox || anyCtr;
  cand[(size_t)b * A_TOT + a] = cd ? 1 : 0;

#pragma unroll
  for (int g = 0; g < NG; ++g) {
    float iv = cd ? iouv[g] : 0.f;
    int cg = (int)gt[g][4];
    float ccg = (cg == 0) ? cc0 : ((cg == 1) ? cc1 : cc2);
    float c = -(ccg + S) - 3.f * logf(iv + 1e-8f) +
              (((bothMask >> g) & 1u) ? 0.f : 100000.f);
    size_t idx = ((size_t)(b * NG + g)) * A_TOT + a;
    ious[idx] = iv;
    cost[idx] = cd ? c : 1e9f;
  }
}

// -------- per-(b,g,chunk): partial top-10 ious + bottom-10 (cost,idx) --------
__global__ __launch_bounds__(256) void k_topk_part(
    const float* __restrict__ ious, const float* __restrict__ cost,
    float* __restrict__ pV, float* __restrict__ pC, int* __restrict__ pI) {
  int s = blockIdx.x, g = blockIdx.y, b = blockIdx.z, tid = threadIdx.x;
  int row = b * NG + g;
  const float* iouRow  = ious + (size_t)row * A_TOT;
  const float* costRow = cost + (size_t)row * A_TOT;
  int lo = s * CHUNK, hi = lo + CHUNK;

  __shared__ float sV[256][11];
  __shared__ float sC[256][11];
  __shared__ int   sI[256][11];

  // per-thread top-10 iou over ~11 strided elements (early-reject guard)
  float tv[10];
#pragma unroll
  for (int j = 0; j < 10; ++j) tv[j] = -1e30f;
  for (int i = lo + tid; i < hi; i += 256) {
    float v = iouRow[i];
    if (v > tv[9]) {
#pragma unroll
      for (int j = 0; j < 10; ++j)
        if (v > tv[j]) { float t = tv[j]; tv[j] = v; v = t; }
    }
  }
#pragma unroll
  for (int j = 0; j < 10; ++j) sV[tid][j] = tv[j];
  sV[tid][10] = -1e30f;

  // per-thread bottom-10 (cost, global idx), lexicographic (guarded)
  float tc[10]; int ti[10];
#pragma unroll
  for (int j = 0; j < 10; ++j) { tc[j] = FLT_MAX; ti[j] = 0x7fffffff; }
  for (int i = lo + tid; i < hi; i += 256) {
    float c = costRow[i]; int ii = i;
    if ((c < tc[9]) || (c == tc[9] && ii < ti[9])) {
#pragma unroll
      for (int j = 0; j < 10; ++j) {
        bool lt = (c < tc[j]) || (c == tc[j] && ii < ti[j]);
        if (lt) {
          float t = tc[j]; tc[j] = c; c = t;
          int t2 = ti[j]; ti[j] = ii; ii = t2;
        }
      }
    }
  }
#pragma unroll
  for (int j = 0; j < 10; ++j) { sC[tid][j] = tc[j]; sI[tid][j] = ti[j]; }
  sC[tid][10] = FLT_MAX; sI[tid][10] = 0x7fffffff;
  __syncthreads();

  for (int half = 128; half >= 1; half >>= 1) {
    if (tid < half) {
      { // iou merge (desc)
        const float* Ar = sV[tid];
        const float* Br = sV[tid + half];
        float out[10]; int pa = 0, pb = 0;
#pragma unroll
        for (int j = 0; j < 10; ++j) {
          float av = Ar[pa], bv = Br[pb];
          bool ta = (av >= bv);
          out[j] = ta ? av : bv;
          pa += ta ? 1 : 0; pb += ta ? 0 : 1;
        }
#pragma unroll
        for (int j = 0; j < 10; ++j) sV[tid][j] = out[j];
      }
      { // cost merge (asc, lexicographic)
        const float* Ac = sC[tid]; const float* Bc = sC[tid + half];
        const int*   Ai = sI[tid]; const int*   Bi = sI[tid + half];
        float oc[10]; int oi[10]; int pa = 0, pb = 0;
#pragma unroll
        for (int j = 0; j < 10; ++j) {
          float ac = Ac[pa], bc = Bc[pb];
          int ai_ = Ai[pa], bi_ = Bi[pb];
          bool ta = (ac < bc) || (ac == bc && ai_ < bi_);
          oc[j] = ta ? ac : bc; oi[j] = ta ? ai_ : bi_;
          pa += ta ? 1 : 0; pb += ta ? 0 : 1;
        }
#pragma unroll
        for (int j = 0; j < 10; ++j) { sC[tid][j] = oc[j]; sI[tid][j] = oi[j]; }
      }
    }
    __syncthreads();
  }

  if (tid < 10) {
    size_t base = ((size_t)row * SPLIT + s) * 10;
    pV[base + tid] = sV[0][tid];
    pC[base + tid] = sC[0][tid];
    pI[base + tid] = sI[0][tid];
  }
}

// -------- per-(b,g): merge 8x10 partials -> dyn_k + threshold (cost,idx) --------
__global__ __launch_bounds__(128) void k_topk_merge(
    const float* __restrict__ pV, const float* __restrict__ pC,
    const int* __restrict__ pI, float* __restrict__ thrC, int* __restrict__ thrI) {
  int g = blockIdx.x, b = blockIdx.y, tid = threadIdx.x;
  int row = b * NG + g;
  constexpr int NC = SPLIT * 10;   // 80 candidates
  __shared__ float sV[NC], sC[NC];
  __shared__ int   sI[NC];
  __shared__ float slot[10];
  __shared__ int kS;

  if (tid < NC) {
    size_t base = (size_t)row * NC + tid;
    sV[tid] = pV[base];
    sC[tid] = pC[base];
    sI[tid] = pI[base];
  }
  __syncthreads();

  float myV = 0.f, myC = 0.f; int myI = 0, rankV = 0;
  if (tid < NC) {
    myV = sV[tid]; myC = sC[tid]; myI = sI[tid];
    for (int j = 0; j < NC; ++j) {
      float v = sV[j];
      rankV += ((v > myV) || (v == myV && j < tid)) ? 1 : 0;
    }
  }
  if (tid < NC && rankV < 10) slot[rankV] = myV;   // ranks 0..9 all exist
  __syncthreads();
  if (tid == 0) {
    float sum = 0.f;
#pragma unroll
    for (int j = 0; j < 10; ++j) sum += slot[j];
    int k = (int)sum; if (k < 1) k = 1;            // dyn_k in [1,10]
    kS = k;
  }
  __syncthreads();
  if (tid < NC) {
    int rankC = 0;
    for (int j = 0; j < NC; ++j) {
      float c = sC[j];
      rankC += ((c < myC) || (c == myC && sI[j] < myI)) ? 1 : 0;
    }
    if (rankC == kS - 1) { thrC[row] = myC; thrI[row] = myI; }
  }
}

// -------- matching resolution + detection loss partials --------
__global__ __launch_bounds__(256) void k_match(
    const float* __restrict__ dec, const float* __restrict__ labels,
    const float* __restrict__ ious, const float* __restrict__ cost,
    const unsigned char* __restrict__ cand,
    const float* __restrict__ thrC, const int* __restrict__ thrI,
    float* __restrict__ pm) {
  __shared__ float gt[NG][5];
  __shared__ float tC[NG];
  __shared__ int   tI[NG];
  int tid = threadIdx.x, b = blockIdx.y;
  if (tid < NG * 5) ((float*)gt)[tid] = labels[b * NG * 5 + tid];
  if (tid >= 128 && tid < 128 + NG) tC[tid - 128] = thrC[b * NG + tid - 128];
  if (tid >= 160 && tid < 160 + NG) tI[tid - 160] = thrI[b * NG + tid - 160];
  __syncthreads();
  int a = blockIdx.x * 256 + tid;

  bool cd = cand[(size_t)b * A_TOT + a] != 0;
  int cnt = 0, firstg = -1, gmin = 0;
  float minc = FLT_MAX, pisum = 0.f, iou_gmin = 0.f;
#pragma unroll
  for (int g = 0; g < NG; ++g) {
    size_t idx = ((size_t)(b * NG + g)) * A_TOT + a;
    float c = cost[idx];
    float iv = ious[idx];
    if (c < minc) { minc = c; gmin = g; iou_gmin = iv; }   // first-argmin
    bool m = cd && ((c < tC[g]) || (c == tC[g] && a <= tI[g]));
    if (m) { cnt++; if (firstg < 0) firstg = g; pisum += iv; }
  }
  if (cnt > 1) { firstg = gmin; pisum = iou_gmin; }  // multi -> best only
  bool fg = cnt > 0;

  const float4* dp = (const float4*)(dec + ((size_t)b * A_TOT + a) * 8);
  float4 d0 = dp[0], d1 = dp[1];
  float l_obj = bcef(d1.x, fg ? 1.f : 0.f);
  float l_iou = 0.f, l_cls = 0.f, nfg = fg ? 1.f : 0.f;
  if (fg) {
    float gx = gt[firstg][0], gy = gt[firstg][1];
    float gw = gt[firstg][2], gh = gt[firstg][3];
    int cg = (int)gt[firstg][4];
    float px = d0.x, py = d0.y, pw = d0.z, ph = d0.w;
    float tlx = fmaxf(px - pw * 0.5f, gx - gw * 0.5f);
    float brx = fminf(px + pw * 0.5f, gx + gw * 0.5f);
    float tly = fmaxf(py - ph * 0.5f, gy - gh * 0.5f);
    float bry = fminf(py + ph * 0.5f, gy + gh * 0.5f);
    float en = ((tlx < brx) && (tly < bry)) ? 1.f : 0.f;
    float ai = (brx - tlx) * (bry - tly) * en;
    float au = pw * ph + gw * gh - ai;
    float iou = ai / (au + 1e-16f);
    l_iou = 1.f - iou * iou;
    l_cls  = bcef(d1.y, (cg == 0) ? pisum : 0.f);
    l_cls += bcef(d1.z, (cg == 1) ? pisum : 0.f);
    l_cls += bcef(d1.w, (cg == 2) ? pisum : 0.f);
  }

  __shared__ float scr[4][4];
  float vals[4] = { nfg, l_iou, l_obj, l_cls };
#pragma unroll
  for (int k = 0; k < 4; ++k) {
    float v = vals[k];
#pragma unroll
    for (int off = 32; off > 0; off >>= 1) v += __shfl_down(v, off, 64);
    if ((tid & 63) == 0) scr[tid >> 6][k] = v;
  }
  __syncthreads();
  if (tid == 0) {
    int bf = blockIdx.y * gridDim.x + blockIdx.x;
#pragma unroll
    for (int k = 0; k < 4; ++k)
      pm[(size_t)bf * 4 + k] = scr[0][k] + scr[1][k] + scr[2][k] + scr[3][k];
  }
}

// -------- mask loss: fused log-softmax CE + dice stats (MLP-heavy version) --------
// 2048 blocks; each block owns 1024 consecutive float4-groups of one batch
// image (256 blocks per image). Each thread fully unrolls 4 groups and issues
// all 16 loads (12 float4 + 4 int4 = 1KB) before any math -> deep MLW.
__global__ __launch_bounds__(256) void k_mask(
    const float* __restrict__ mi, const int* __restrict__ ml,
    float* __restrict__ pk) {
  int tid = threadIdx.x;
  int blk = blockIdx.x;
  int b  = blk >> 8;                 // 256 blocks per batch image
  int g0 = (blk & 255) << 10;        // float4-group offset within image
  const float* base0 = mi + (size_t)b * 3 * HW_M + (size_t)g0 * 4;
  const int*   lbase = ml + ((size_t)b << 20) + (size_t)g0 * 4;

  float4 x0[4], x1[4], x2[4]; int4 lb[4];
#pragma unroll
  for (int u = 0; u < 4; ++u) {
    size_t off = (size_t)(tid + u * 256) * 4;
    x0[u] = *(const float4*)(base0 + off);
    x1[u] = *(const float4*)(base0 + HW_M + off);
    x2[u] = *(const float4*)(base0 + 2 * HW_M + off);
    lb[u] = *(const int4*)(lbase + off);
  }

  float ce = 0.f, tp0 = 0, tp1 = 0, tp2 = 0;
  float ss0 = 0, ss1 = 0, ss2 = 0, c0 = 0, c1 = 0, c2 = 0;

  auto proc = [&](float v0, float v1, float v2, int l) {
    float m = fmaxf(v0, fmaxf(v1, v2));
    float e0 = expf(v0 - m), e1 = expf(v1 - m), e2 = expf(v2 - m);
    float sum = e0 + e1 + e2;
    float lse = m + logf(sum);
    float inv = 1.f / sum;
    float s0 = e0 * inv, s1 = e1 * inv, s2 = e2 * inv;
    ss0 += s0; ss1 += s1; ss2 += s2;
    if (l == 0)      { ce += v0 - lse; tp0 += s0; c0 += 1.f; }
    else if (l == 1) { ce += v1 - lse; tp1 += s1; c1 += 1.f; }
    else             { ce += v2 - lse; tp2 += s2; c2 += 1.f; }
  };

#pragma unroll
  for (int u = 0; u < 4; ++u) {
    proc(x0[u].x, x1[u].x, x2[u].x, lb[u].x);
    proc(x0[u].y, x1[u].y, x2[u].y, lb[u].y);
    proc(x0[u].z, x1[u].z, x2[u].z, lb[u].z);
    proc(x0[u].w, x1[u].w, x2[u].w, lb[u].w);
  }

  __shared__ float scr[4][10];
  float vals[10] = { ce, tp0, tp1, tp2, ss0, ss1, ss2, c0, c1, c2 };
#pragma unroll
  for (int k = 0; k < 10; ++k) {
    float v = vals[k];
#pragma unroll
    for (int off = 32; off > 0; off >>= 1) v += __shfl_down(v, off, 64);
    if ((tid & 63) == 0) scr[tid >> 6][k] = v;
  }
  __syncthreads();
  if (tid == 0) {
#pragma unroll
    for (int k = 0; k < 10; ++k)
      pk[(size_t)blk * 10 + k] = scr[0][k] + scr[1][k] + scr[2][k] + scr[3][k];
  }
}

// -------- final reduce + output --------
__device__ __forceinline__ float bsum256(float v, float* scr) {
#pragma unroll
  for (int off = 32; off > 0; off >>= 1) v += __shfl_down(v, off, 64);
  __syncthreads();
  if ((threadIdx.x & 63) == 0) scr[threadIdx.x >> 6] = v;
  __syncthreads();
  return scr[0] + scr[1] + scr[2] + scr[3];
}

__global__ __launch_bounds__(256) void k_final(
    const float* __restrict__ pm, const float* __restrict__ pk,
    float* __restrict__ out) {
  __shared__ float scr[4];
  int tid = threadIdx.x;
  float t0 = 0, t1 = 0, t2 = 0, t3 = 0;
  for (int r = tid; r < 672; r += 256) {
    t0 += pm[(size_t)r * 4 + 0];
    t1 += pm[(size_t)r * 4 + 1];
    t2 += pm[(size_t)r * 4 + 2];
    t3 += pm[(size_t)r * 4 + 3];
  }
  float u[10] = {0,0,0,0,0,0,0,0,0,0};
  for (int r = tid; r < MBLK; r += 256) {
#pragma unroll
    for (int k = 0; k < 10; ++k) u[k] += pk[(size_t)r * 10 + k];
  }
  float S_nfg = bsum256(t0, scr);
  float S_iou = bsum256(t1, scr);
  float S_obj = bsum256(t2, scr);
  float S_cls = bsum256(t3, scr);
  float S_ce  = bsum256(u[0], scr);
  float S_tp0 = bsum256(u[1], scr);
  float S_tp1 = bsum256(u[2], scr);
  float S_tp2 = bsum256(u[3], scr);
  float S_ss0 = bsum256(u[4], scr);
  float S_ss1 = bsum256(u[5], scr);
  float S_ss2 = bsum256(u[6], scr);
  float S_c0  = bsum256(u[7], scr);
  float S_c1  = bsum256(u[8], scr);
  float S_c2  = bsum256(u[9], scr);

  if (tid == 0) {
    float nfg = fmaxf(S_nfg, 1.f);
    float o1 = 5.f * S_iou / nfg;
    float o2 = S_obj / nfg;
    float o3 = S_cls / nfg;
    float ce = -S_ce / (float)((long long)NB << 20);
    float tps[3] = { S_tp0, S_tp1, S_tp2 };
    float sss[3] = { S_ss0, S_ss1, S_ss2 };
    float cns[3] = { S_c0, S_c1, S_c2 };
    float ds = 0.f;
#pragma unroll
    for (int c = 0; c < 3; ++c) {
      float tp = tps[c];
      float fp = sss[c] - tp;
      float fn = cns[c] - tp;
      ds += (2.f * tp + 1e-5f) / (2.f * tp + fn + fp + 1e-5f);
    }
    float dice = 1.f - ds / 3.f;
    float o4 = ce + dice;
    out[0] = o1 + o2 + o3 + o4;
    out[1] = o1;
    out[2] = o2;
    out[3] = o3;
    out[4] = o4;
    out[5] = 0.f;
  }
}

extern "C" void kernel_launch(void* const* d_in, const int* in_sizes, int n_in,
                              void* d_out, int out_size, void* d_ws, size_t ws_size,
                              hipStream_t stream) {
  const float* p3     = (const float*)d_in[0];
  const float* p4     = (const float*)d_in[1];
  const float* p5     = (const float*)d_in[2];
  const float* mi     = (const float*)d_in[3];
  const float* labels = (const float*)d_in[4];
  // d_in[5] input_images: unused by the loss
  const int*   ml     = (const int*)d_in[6];
  // d_in[7] now_epoch: unused

  float* ws   = (float*)d_ws;
  float* dec  = ws + OFF_DEC;
  float* ious = ws + OFF_IOUS;
  float* cost = ws + OFF_COST;
  float* thrC = ws + OFF_THRC;
  int*   thrI = (int*)(ws + OFF_THRI);
  unsigned char* cand = (unsigned char*)(ws + OFF_CAND);
  float* pm   = ws + OFF_PM;
  float* pk   = ws + OFF_PK;
  float* pV   = ws + OFF_PV;
  float* pC   = ws + OFF_PC;
  int*   pI   = (int*)(ws + OFF_PI);
  float* out  = (float*)d_out;

  dim3 gA(A_TOT / 256, NB);   // 21504 = 84*256 exactly
  k_cost<<<gA, 256, 0, stream>>>(p3, p4, p5, labels, dec, ious, cost, cand);
  k_topk_part<<<dim3(SPLIT, NG, NB), 256, 0, stream>>>(ious, cost, pV, pC, pI);
  k_topk_merge<<<dim3(NG, NB), 128, 0, stream>>>(pV, pC, pI, thrC, thrI);
  k_match<<<gA, 256, 0, stream>>>(dec, labels, ious, cost, cand, thrC, thrI, pm);
  k_mask<<<MBLK, 256, 0, stream>>>(mi, ml, pk);
  k_final<<<1, 256, 0, stream>>>(pm, pk, out);
}

// Round 5
// 121.976 us; speedup vs baseline: 1.3179x; 1.3179x over previous
//
#include <hip/hip_runtime.h>
#include <cfloat>

// ---- problem constants (fixed by setup_inputs) ----
constexpr int A_TOT = 21504;      // 128^2 + 64^2 + 32^2
constexpr int NB    = 8;
constexpr int NG    = 20;
constexpr int HW_M  = 1 << 20;    // 1024*1024
constexpr int SPLIT = 8;          // chunks per (b,g) row for top-k
constexpr int CHUNK = A_TOT / SPLIT;   // 2688
constexpr int MBLK  = 2048;       // k_mask blocks (256 per batch image)

constexpr float L2E = 1.44269504088896340736f;
constexpr float LN2 = 0.69314718055994530942f;

// ---- workspace layout (float offsets) ----
constexpr size_t OFF_DEC  = 0;
constexpr size_t SZ_DEC   = (size_t)NB * A_TOT * 8;            // 1,376,256
constexpr size_t OFF_IOUS = OFF_DEC + SZ_DEC;
constexpr size_t SZ_GA    = (size_t)NB * NG * A_TOT;           // 3,440,640
constexpr size_t OFF_COST = OFF_IOUS + SZ_GA;
constexpr size_t OFF_THRC = OFF_COST + SZ_GA;                  // NB*NG floats
constexpr size_t OFF_THRI = OFF_THRC + NB * NG;                // NB*NG ints
constexpr size_t OFF_CAND = OFF_THRI + NB * NG;                // NB*A_TOT bytes
constexpr size_t OFF_PM   = OFF_CAND + (NB * A_TOT) / 4;       // 672*4 floats
constexpr size_t OFF_PK   = OFF_PM + 672 * 4;                  // MBLK*10 floats
constexpr size_t OFF_PV   = OFF_PK + (size_t)MBLK * 10;        // part iou vals
constexpr size_t SZ_PART  = (size_t)NB * NG * SPLIT * 10;      // 12,800
constexpr size_t OFF_PC   = OFF_PV + SZ_PART;                  // part costs
constexpr size_t OFF_PI   = OFF_PC + SZ_PART;                  // part idx (int)

// ---- fast transcendentals: single HW instruction each (~1 ulp) ----
// NOTE: __builtin_amdgcn_logf IS the v_log_f32 (log2) instruction on
// ROCm/clang — __clang_hip_math.h implements __log2f with it. There is no
// __builtin_amdgcn_log2f.
__device__ __forceinline__ float hw_exp2(float x) { return __builtin_amdgcn_exp2f(x); }
__device__ __forceinline__ float hw_log2(float x) { return __builtin_amdgcn_logf(x); }
__device__ __forceinline__ float fexp(float x) { return hw_exp2(x * L2E); }   // e^x
__device__ __forceinline__ float flog(float x) { return hw_log2(x) * LN2; }   // ln(x)
__device__ __forceinline__ float frcp(float x) { return __builtin_amdgcn_rcpf(x); }
__device__ __forceinline__ float fsig(float x) { return frcp(1.f + fexp(-x)); }
__device__ __forceinline__ float fbce(float x, float y) {
  // max(x,0) - x*y + log1p(exp(-|x|))
  float t = hw_exp2(-fabsf(x) * L2E);
  return fmaxf(x, 0.f) - x * y + LN2 * hw_log2(1.f + t);
}
__device__ __forceinline__ void anchor_geom(int a, int& hw, int& lw, float& st) {
  if (a < 16384)      { hw = a;         lw = 7; st = 8.f;  }
  else if (a < 20480) { hw = a - 16384; lw = 6; st = 16.f; }
  else                { hw = a - 20480; lw = 5; st = 32.f; }
}

// -------- fused decode + cost/iou/cand: per-(b,a) thread loops 20 gts --------
__global__ __launch_bounds__(256) void k_cost(
    const float* __restrict__ p3, const float* __restrict__ p4,
    const float* __restrict__ p5, const float* __restrict__ labels,
    float* __restrict__ dec, float* __restrict__ ious,
    float* __restrict__ cost, unsigned char* __restrict__ cand) {
  __shared__ float gt[NG][5];
  int tid = threadIdx.x, b = blockIdx.y;
  if (tid < NG * 5) ((float*)gt)[tid] = labels[b * NG * 5 + tid];
  __syncthreads();
  int a = blockIdx.x * 256 + tid;

  // ---- inline decode ----
  int hw, lw; float st;
  anchor_geom(a, hw, lw, st);
  const float* src; int HW;
  if (a < 16384)      { src = p3; HW = 16384; }
  else if (a < 20480) { src = p4; HW = 4096;  }
  else                { src = p5; HW = 1024;  }
  int x = hw & ((1 << lw) - 1), y = hw >> lw;
  const float* c0 = src + (size_t)b * 8 * HW + hw;
  float o0 = c0[0];
  float o1 = c0[(size_t)HW];
  float o2 = c0[(size_t)2 * HW];
  float o3 = c0[(size_t)3 * HW];
  float o4 = c0[(size_t)4 * HW];
  float o5 = c0[(size_t)5 * HW];
  float o6 = c0[(size_t)6 * HW];
  float o7 = c0[(size_t)7 * HW];
  float px = (o0 + (float)x) * st, py = (o1 + (float)y) * st;
  float pw = fexp(o2) * st,        ph = fexp(o3) * st;
  {
    float4* dst = (float4*)(dec + ((size_t)b * A_TOT + a) * 8);
    dst[0] = make_float4(px, py, pw, ph);
    dst[1] = make_float4(o4, o5, o6, o7);
  }

  float xc = ((float)x + 0.5f) * st, yc = ((float)y + 0.5f) * st;

  // per-anchor class-cost pieces: cls_cost(g) = -(cc[cg] + S)
  float so = fsig(o4);
  float cc0, cc1, cc2, S;
  {
    float q0 = sqrtf(fsig(o5) * so);
    float q1 = sqrtf(fsig(o6) * so);
    float q2 = sqrtf(fsig(o7) * so);
    float lg0 = flog(q0 + 1e-8f), lg1 = flog(q1 + 1e-8f), lg2 = flog(q2 + 1e-8f);
    float m0 = flog(1.f - q0 + 1e-8f), m1 = flog(1.f - q1 + 1e-8f), m2 = flog(1.f - q2 + 1e-8f);
    S = m0 + m1 + m2;
    cc0 = lg0 - m0; cc1 = lg1 - m1; cc2 = lg2 - m2;
  }

  float iouv[NG];
  unsigned bothMask = 0;
  bool anyBox = false, anyCtr = false;
  float hpw = pw * 0.5f, hph = ph * 0.5f;
  float plx = px - hpw, prx = px + hpw, pty = py - hph, pby = py + hph;
  float parea = pw * ph;
  float r = 2.5f * st;

#pragma unroll
  for (int g = 0; g < NG; ++g) {
    float gx = gt[g][0], gy = gt[g][1], gw = gt[g][2], gh = gt[g][3];
    float hgw = gw * 0.5f, hgh = gh * 0.5f;
    float glx = gx - hgw, grx = gx + hgw, gty = gy - hgh, gby = gy + hgh;
    bool ib = (xc > glx) && (xc < grx) && (yc > gty) && (yc < gby);
    bool ic = (xc > gx - r) && (xc < gx + r) && (yc > gy - r) && (yc < gy + r);
    anyBox |= ib; anyCtr |= ic;
    if (ib && ic) bothMask |= (1u << g);
    float tlx = fmaxf(glx, plx), brx = fminf(grx, prx);
    float tly = fmaxf(gty, pty), bry = fminf(gby, pby);
    float en = ((tlx < brx) && (tly < bry)) ? 1.f : 0.f;
    float ai = (brx - tlx) * (bry - tly) * en;
    float au = gw * gh + parea - ai;
    iouv[g] = ai / (au + 1e-16f);
  }
  bool cd = anyBox || anyCtr;
  cand[(size_t)b * A_TOT + a] = cd ? 1 : 0;

#pragma unroll
  for (int g = 0; g < NG; ++g) {
    float iv = cd ? iouv[g] : 0.f;
    int cg = (int)gt[g][4];
    float ccg = (cg == 0) ? cc0 : ((cg == 1) ? cc1 : cc2);
    float c = -(ccg + S) - 3.f * flog(iv + 1e-8f) +
              (((bothMask >> g) & 1u) ? 0.f : 100000.f);
    size_t idx = ((size_t)(b * NG + g)) * A_TOT + a;
    ious[idx] = iv;
    cost[idx] = cd ? c : 1e9f;
  }
}

// -------- per-(b,g,chunk): partial top-10 ious + bottom-10 (cost,idx) --------
__global__ __launch_bounds__(256) void k_topk_part(
    const float* __restrict__ ious, const float* __restrict__ cost,
    float* __restrict__ pV, float* __restrict__ pC, int* __restrict__ pI) {
  int s = blockIdx.x, g = blockIdx.y, b = blockIdx.z, tid = threadIdx.x;
  int row = b * NG + g;
  const float* iouRow  = ious + (size_t)row * A_TOT;
  const float* costRow = cost + (size_t)row * A_TOT;
  int lo = s * CHUNK, hi = lo + CHUNK;

  __shared__ float sV[256][11];
  __shared__ float sC[256][11];
  __shared__ int   sI[256][11];

  // per-thread top-10 iou over ~11 strided elements (early-reject guard)
  float tv[10];
#pragma unroll
  for (int j = 0; j < 10; ++j) tv[j] = -1e30f;
  for (int i = lo + tid; i < hi; i += 256) {
    float v = iouRow[i];
    if (v > tv[9]) {
#pragma unroll
      for (int j = 0; j < 10; ++j)
        if (v > tv[j]) { float t = tv[j]; tv[j] = v; v = t; }
    }
  }
#pragma unroll
  for (int j = 0; j < 10; ++j) sV[tid][j] = tv[j];
  sV[tid][10] = -1e30f;

  // per-thread bottom-10 (cost, global idx), lexicographic (guarded)
  float tc[10]; int ti[10];
#pragma unroll
  for (int j = 0; j < 10; ++j) { tc[j] = FLT_MAX; ti[j] = 0x7fffffff; }
  for (int i = lo + tid; i < hi; i += 256) {
    float c = costRow[i]; int ii = i;
    if ((c < tc[9]) || (c == tc[9] && ii < ti[9])) {
#pragma unroll
      for (int j = 0; j < 10; ++j) {
        bool lt = (c < tc[j]) || (c == tc[j] && ii < ti[j]);
        if (lt) {
          float t = tc[j]; tc[j] = c; c = t;
          int t2 = ti[j]; ti[j] = ii; ii = t2;
        }
      }
    }
  }
#pragma unroll
  for (int j = 0; j < 10; ++j) { sC[tid][j] = tc[j]; sI[tid][j] = ti[j]; }
  sC[tid][10] = FLT_MAX; sI[tid][10] = 0x7fffffff;
  __syncthreads();

  for (int half = 128; half >= 1; half >>= 1) {
    if (tid < half) {
      { // iou merge (desc)
        const float* Ar = sV[tid];
        const float* Br = sV[tid + half];
        float out[10]; int pa = 0, pb = 0;
#pragma unroll
        for (int j = 0; j < 10; ++j) {
          float av = Ar[pa], bv = Br[pb];
          bool ta = (av >= bv);
          out[j] = ta ? av : bv;
          pa += ta ? 1 : 0; pb += ta ? 0 : 1;
        }
#pragma unroll
        for (int j = 0; j < 10; ++j) sV[tid][j] = out[j];
      }
      { // cost merge (asc, lexicographic)
        const float* Ac = sC[tid]; const float* Bc = sC[tid + half];
        const int*   Ai = sI[tid]; const int*   Bi = sI[tid + half];
        float oc[10]; int oi[10]; int pa = 0, pb = 0;
#pragma unroll
        for (int j = 0; j < 10; ++j) {
          float ac = Ac[pa], bc = Bc[pb];
          int ai_ = Ai[pa], bi_ = Bi[pb];
          bool ta = (ac < bc) || (ac == bc && ai_ < bi_);
          oc[j] = ta ? ac : bc; oi[j] = ta ? ai_ : bi_;
          pa += ta ? 1 : 0; pb += ta ? 0 : 1;
        }
#pragma unroll
        for (int j = 0; j < 10; ++j) { sC[tid][j] = oc[j]; sI[tid][j] = oi[j]; }
      }
    }
    __syncthreads();
  }

  if (tid < 10) {
    size_t base = ((size_t)row * SPLIT + s) * 10;
    pV[base + tid] = sV[0][tid];
    pC[base + tid] = sC[0][tid];
    pI[base + tid] = sI[0][tid];
  }
}

// -------- per-(b,g): merge 8x10 partials -> dyn_k + threshold (cost,idx) --------
__global__ __launch_bounds__(128) void k_topk_merge(
    const float* __restrict__ pV, const float* __restrict__ pC,
    const int* __restrict__ pI, float* __restrict__ thrC, int* __restrict__ thrI) {
  int g = blockIdx.x, b = blockIdx.y, tid = threadIdx.x;
  int row = b * NG + g;
  constexpr int NC = SPLIT * 10;   // 80 candidates
  __shared__ float sV[NC], sC[NC];
  __shared__ int   sI[NC];
  __shared__ float slot[10];
  __shared__ int kS;

  if (tid < NC) {
    size_t base = (size_t)row * NC + tid;
    sV[tid] = pV[base];
    sC[tid] = pC[base];
    sI[tid] = pI[base];
  }
  __syncthreads();

  float myV = 0.f, myC = 0.f; int myI = 0, rankV = 0;
  if (tid < NC) {
    myV = sV[tid]; myC = sC[tid]; myI = sI[tid];
    for (int j = 0; j < NC; ++j) {
      float v = sV[j];
      rankV += ((v > myV) || (v == myV && j < tid)) ? 1 : 0;
    }
  }
  if (tid < NC && rankV < 10) slot[rankV] = myV;   // ranks 0..9 all exist
  __syncthreads();
  if (tid == 0) {
    float sum = 0.f;
#pragma unroll
    for (int j = 0; j < 10; ++j) sum += slot[j];
    int k = (int)sum; if (k < 1) k = 1;            // dyn_k in [1,10]
    kS = k;
  }
  __syncthreads();
  if (tid < NC) {
    int rankC = 0;
    for (int j = 0; j < NC; ++j) {
      float c = sC[j];
      rankC += ((c < myC) || (c == myC && sI[j] < myI)) ? 1 : 0;
    }
    if (rankC == kS - 1) { thrC[row] = myC; thrI[row] = myI; }
  }
}

// -------- matching resolution + detection loss partials --------
__global__ __launch_bounds__(256) void k_match(
    const float* __restrict__ dec, const float* __restrict__ labels,
    const float* __restrict__ ious, const float* __restrict__ cost,
    const unsigned char* __restrict__ cand,
    const float* __restrict__ thrC, const int* __restrict__ thrI,
    float* __restrict__ pm) {
  __shared__ float gt[NG][5];
  __shared__ float tC[NG];
  __shared__ int   tI[NG];
  int tid = threadIdx.x, b = blockIdx.y;
  if (tid < NG * 5) ((float*)gt)[tid] = labels[b * NG * 5 + tid];
  if (tid >= 128 && tid < 128 + NG) tC[tid - 128] = thrC[b * NG + tid - 128];
  if (tid >= 160 && tid < 160 + NG) tI[tid - 160] = thrI[b * NG + tid - 160];
  __syncthreads();
  int a = blockIdx.x * 256 + tid;

  bool cd = cand[(size_t)b * A_TOT + a] != 0;
  int cnt = 0, firstg = -1, gmin = 0;
  float minc = FLT_MAX, pisum = 0.f, iou_gmin = 0.f;
#pragma unroll
  for (int g = 0; g < NG; ++g) {
    size_t idx = ((size_t)(b * NG + g)) * A_TOT + a;
    float c = cost[idx];
    float iv = ious[idx];
    if (c < minc) { minc = c; gmin = g; iou_gmin = iv; }   // first-argmin
    bool m = cd && ((c < tC[g]) || (c == tC[g] && a <= tI[g]));
    if (m) { cnt++; if (firstg < 0) firstg = g; pisum += iv; }
  }
  if (cnt > 1) { firstg = gmin; pisum = iou_gmin; }  // multi -> best only
  bool fg = cnt > 0;

  const float4* dp = (const float4*)(dec + ((size_t)b * A_TOT + a) * 8);
  float4 d0 = dp[0], d1 = dp[1];
  float l_obj = fbce(d1.x, fg ? 1.f : 0.f);
  float l_iou = 0.f, l_cls = 0.f, nfg = fg ? 1.f : 0.f;
  if (fg) {
    float gx = gt[firstg][0], gy = gt[firstg][1];
    float gw = gt[firstg][2], gh = gt[firstg][3];
    int cg = (int)gt[firstg][4];
    float px = d0.x, py = d0.y, pw = d0.z, ph = d0.w;
    float tlx = fmaxf(px - pw * 0.5f, gx - gw * 0.5f);
    float brx = fminf(px + pw * 0.5f, gx + gw * 0.5f);
    float tly = fmaxf(py - ph * 0.5f, gy - gh * 0.5f);
    float bry = fminf(py + ph * 0.5f, gy + gh * 0.5f);
    float en = ((tlx < brx) && (tly < bry)) ? 1.f : 0.f;
    float ai = (brx - tlx) * (bry - tly) * en;
    float au = pw * ph + gw * gh - ai;
    float iou = ai / (au + 1e-16f);
    l_iou = 1.f - iou * iou;
    l_cls  = fbce(d1.y, (cg == 0) ? pisum : 0.f);
    l_cls += fbce(d1.z, (cg == 1) ? pisum : 0.f);
    l_cls += fbce(d1.w, (cg == 2) ? pisum : 0.f);
  }

  __shared__ float scr[4][4];
  float vals[4] = { nfg, l_iou, l_obj, l_cls };
#pragma unroll
  for (int k = 0; k < 4; ++k) {
    float v = vals[k];
#pragma unroll
    for (int off = 32; off > 0; off >>= 1) v += __shfl_down(v, off, 64);
    if ((tid & 63) == 0) scr[tid >> 6][k] = v;
  }
  __syncthreads();
  if (tid == 0) {
    int bf = blockIdx.y * gridDim.x + blockIdx.x;
#pragma unroll
    for (int k = 0; k < 4; ++k)
      pm[(size_t)bf * 4 + k] = scr[0][k] + scr[1][k] + scr[2][k] + scr[3][k];
  }
}

// -------- mask loss: fused softmax CE + dice stats (HW-trans version) --------
// 2048 blocks; each block owns 1024 consecutive float4-groups of one batch
// image. All 16 loads issued upfront; softmax-3 without max-subtraction
// (|v| small, no overflow) using v_exp/v_log/v_rcp -> ~30 VALU/pixel.
__global__ __launch_bounds__(256) void k_mask(
    const float* __restrict__ mi, const int* __restrict__ ml,
    float* __restrict__ pk) {
  int tid = threadIdx.x;
  int blk = blockIdx.x;
  int b  = blk >> 8;                 // 256 blocks per batch image
  int g0 = (blk & 255) << 10;        // float4-group offset within image
  const float* base0 = mi + (size_t)b * 3 * HW_M + (size_t)g0 * 4;
  const int*   lbase = ml + ((size_t)b << 20) + (size_t)g0 * 4;

  float4 x0[4], x1[4], x2[4]; int4 lb[4];
#pragma unroll
  for (int u = 0; u < 4; ++u) {
    size_t off = (size_t)(tid + u * 256) * 4;
    x0[u] = *(const float4*)(base0 + off);
    x1[u] = *(const float4*)(base0 + HW_M + off);
    x2[u] = *(const float4*)(base0 + 2 * HW_M + off);
    lb[u] = *(const int4*)(lbase + off);
  }

  float ce = 0.f, tp0 = 0, tp1 = 0, tp2 = 0;
  float ss0 = 0, ss1 = 0;            // ss2 derived at the end
  float c0 = 0, c1 = 0;              // c2 derived at the end

  auto proc = [&](float v0, float v1, float v2, int l) {
    float e0 = hw_exp2(v0 * L2E);
    float e1 = hw_exp2(v1 * L2E);
    float e2 = hw_exp2(v2 * L2E);
    float sum = e0 + e1 + e2;
    float inv = __builtin_amdgcn_rcpf(sum);
    float lse = hw_log2(sum) * LN2;
    float s0 = e0 * inv, s1 = e1 * inv;
    ss0 += s0; ss1 += s1;
    bool l0 = (l == 0), l1 = (l == 1);
    float vl = l0 ? v0 : (l1 ? v1 : v2);
    float el = l0 ? e0 : (l1 ? e1 : e2);
    float sl = el * inv;
    ce += vl - lse;
    tp0 += l0 ? sl : 0.f;
    tp1 += l1 ? sl : 0.f;
    tp2 += (!l0 && !l1) ? sl : 0.f;
    c0 += l0 ? 1.f : 0.f;
    c1 += l1 ? 1.f : 0.f;
  };

#pragma unroll
  for (int u = 0; u < 4; ++u) {
    proc(x0[u].x, x1[u].x, x2[u].x, lb[u].x);
    proc(x0[u].y, x1[u].y, x2[u].y, lb[u].y);
    proc(x0[u].z, x1[u].z, x2[u].z, lb[u].z);
    proc(x0[u].w, x1[u].w, x2[u].w, lb[u].w);
  }
  // ss2/c2 derived: per-pixel s0+s1+s2 = sum*rcp(sum) ≈ 1 (±1ulp of rcp);
  // total deviation over 8M pixels ~1e-4 -> far below the 14.96 threshold.
  float ss2 = 16.f - ss0 - ss1;
  float c2 = 16.f - c0 - c1;

  __shared__ float scr[4][10];
  float vals[10] = { ce, tp0, tp1, tp2, ss0, ss1, ss2, c0, c1, c2 };
#pragma unroll
  for (int k = 0; k < 10; ++k) {
    float v = vals[k];
#pragma unroll
    for (int off = 32; off > 0; off >>= 1) v += __shfl_down(v, off, 64);
    if ((tid & 63) == 0) scr[tid >> 6][k] = v;
  }
  __syncthreads();
  if (tid == 0) {
#pragma unroll
    for (int k = 0; k < 10; ++k)
      pk[(size_t)blk * 10 + k] = scr[0][k] + scr[1][k] + scr[2][k] + scr[3][k];
  }
}

// -------- final reduce + output --------
__device__ __forceinline__ float bsum256(float v, float* scr) {
#pragma unroll
  for (int off = 32; off > 0; off >>= 1) v += __shfl_down(v, off, 64);
  __syncthreads();
  if ((threadIdx.x & 63) == 0) scr[threadIdx.x >> 6] = v;
  __syncthreads();
  return scr[0] + scr[1] + scr[2] + scr[3];
}

__global__ __launch_bounds__(256) void k_final(
    const float* __restrict__ pm, const float* __restrict__ pk,
    float* __restrict__ out) {
  __shared__ float scr[4];
  int tid = threadIdx.x;
  float t0 = 0, t1 = 0, t2 = 0, t3 = 0;
  for (int r = tid; r < 672; r += 256) {
    t0 += pm[(size_t)r * 4 + 0];
    t1 += pm[(size_t)r * 4 + 1];
    t2 += pm[(size_t)r * 4 + 2];
    t3 += pm[(size_t)r * 4 + 3];
  }
  float u[10] = {0,0,0,0,0,0,0,0,0,0};
  for (int r = tid; r < MBLK; r += 256) {
#pragma unroll
    for (int k = 0; k < 10; ++k) u[k] += pk[(size_t)r * 10 + k];
  }
  float S_nfg = bsum256(t0, scr);
  float S_iou = bsum256(t1, scr);
  float S_obj = bsum256(t2, scr);
  float S_cls = bsum256(t3, scr);
  float S_ce  = bsum256(u[0], scr);
  float S_tp0 = bsum256(u[1], scr);
  float S_tp1 = bsum256(u[2], scr);
  float S_tp2 = bsum256(u[3], scr);
  float S_ss0 = bsum256(u[4], scr);
  float S_ss1 = bsum256(u[5], scr);
  float S_ss2 = bsum256(u[6], scr);
  float S_c0  = bsum256(u[7], scr);
  float S_c1  = bsum256(u[8], scr);
  float S_c2  = bsum256(u[9], scr);

  if (tid == 0) {
    float nfg = fmaxf(S_nfg, 1.f);
    float o1 = 5.f * S_iou / nfg;
    float o2 = S_obj / nfg;
    float o3 = S_cls / nfg;
    float ce = -S_ce / (float)((long long)NB << 20);
    float tps[3] = { S_tp0, S_tp1, S_tp2 };
    float sss[3] = { S_ss0, S_ss1, S_ss2 };
    float cns[3] = { S_c0, S_c1, S_c2 };
    float ds = 0.f;
#pragma unroll
    for (int c = 0; c < 3; ++c) {
      float tp = tps[c];
      float fp = sss[c] - tp;
      float fn = cns[c] - tp;
      ds += (2.f * tp + 1e-5f) / (2.f * tp + fn + fp + 1e-5f);
    }
    float dice = 1.f - ds / 3.f;
    float o4 = ce + dice;
    out[0] = o1 + o2 + o3 + o4;
    out[1] = o1;
    out[2] = o2;
    out[3] = o3;
    out[4] = o4;
    out[5] = 0.f;
  }
}

extern "C" void kernel_launch(void* const* d_in, const int* in_sizes, int n_in,
                              void* d_out, int out_size, void* d_ws, size_t ws_size,
                              hipStream_t stream) {
  const float* p3     = (const float*)d_in[0];
  const float* p4     = (const float*)d_in[1];
  const float* p5     = (const float*)d_in[2];
  const float* mi     = (const float*)d_in[3];
  const float* labels = (const float*)d_in[4];
  // d_in[5] input_images: unused by the loss
  const int*   ml     = (const int*)d_in[6];
  // d_in[7] now_epoch: unused

  float* ws   = (float*)d_ws;
  float* dec  = ws + OFF_DEC;
  float* ious = ws + OFF_IOUS;
  float* cost = ws + OFF_COST;
  float* thrC = ws + OFF_THRC;
  int*   thrI = (int*)(ws + OFF_THRI);
  unsigned char* cand = (unsigned char*)(ws + OFF_CAND);
  float* pm   = ws + OFF_PM;
  float* pk   = ws + OFF_PK;
  float* pV   = ws + OFF_PV;
  float* pC   = ws + OFF_PC;
  int*   pI   = (int*)(ws + OFF_PI);
  float* out  = (float*)d_out;

  dim3 gA(A_TOT / 256, NB);   // 21504 = 84*256 exactly
  k_cost<<<gA, 256, 0, stream>>>(p3, p4, p5, labels, dec, ious, cost, cand);
  k_topk_part<<<dim3(SPLIT, NG, NB), 256, 0, stream>>>(ious, cost, pV, pC, pI);
  k_topk_merge<<<dim3(NG, NB), 128, 0, stream>>>(pV, pC, pI, thrC, thrI);
  k_match<<<gA, 256, 0, stream>>>(dec, labels, ious, cost, cand, thrC, thrI, pm);
  k_mask<<<MBLK, 256, 0, stream>>>(mi, ml, pk);
  k_final<<<1, 256, 0, stream>>>(pm, pk, out);
}

// Round 7
// 104.458 us; speedup vs baseline: 1.5389x; 1.1677x over previous
//
#include <hip/hip_runtime.h>
#include <cfloat>

// ---- problem constants (fixed by setup_inputs) ----
constexpr int A_TOT = 21504;      // 128^2 + 64^2 + 32^2
constexpr int NB    = 8;
constexpr int NG    = 20;
constexpr int HW_M  = 1 << 20;    // 1024*1024
constexpr int SPLIT = 16;         // chunks per (b,g) row for top-k
constexpr int CHUNK = A_TOT / SPLIT;   // 1344
constexpr int MBLK  = 2048;       // k_mask blocks (256 per batch image)

constexpr float L2E = 1.44269504088896340736f;
constexpr float LN2 = 0.69314718055994530942f;

// ---- workspace layout (float offsets) ----
constexpr size_t OFF_DEC  = 0;
constexpr size_t SZ_DEC   = (size_t)NB * A_TOT * 8;            // 1,376,256
constexpr size_t OFF_IOUS = OFF_DEC + SZ_DEC;
constexpr size_t SZ_GA    = (size_t)NB * NG * A_TOT;           // 3,440,640
constexpr size_t OFF_COST = OFF_IOUS + SZ_GA;
constexpr size_t OFF_THRC = OFF_COST + SZ_GA;                  // NB*NG floats
constexpr size_t OFF_THRI = OFF_THRC + NB * NG;                // NB*NG ints
constexpr size_t OFF_CAND = OFF_THRI + NB * NG;                // NB*A_TOT bytes
constexpr size_t OFF_PM   = OFF_CAND + (NB * A_TOT) / 4;       // 672*4 floats
constexpr size_t OFF_PK   = OFF_PM + 672 * 4;                  // MBLK*10 floats
constexpr size_t OFF_PV   = OFF_PK + (size_t)MBLK * 10;        // part iou vals
constexpr size_t SZ_PART  = (size_t)NB * NG * SPLIT * 10;      // 25,600
constexpr size_t OFF_PC   = OFF_PV + SZ_PART;                  // part costs
constexpr size_t OFF_PI   = OFF_PC + SZ_PART;                  // part idx (int)

// ---- fast transcendentals: single HW instruction each (~1 ulp) ----
// NOTE: __builtin_amdgcn_logf IS v_log_f32 (log2) on ROCm/clang; there is no
// __builtin_amdgcn_log2f.
__device__ __forceinline__ float hw_exp2(float x) { return __builtin_amdgcn_exp2f(x); }
__device__ __forceinline__ float hw_log2(float x) { return __builtin_amdgcn_logf(x); }
__device__ __forceinline__ float fexp(float x) { return hw_exp2(x * L2E); }   // e^x
__device__ __forceinline__ float flog(float x) { return hw_log2(x) * LN2; }   // ln(x)
__device__ __forceinline__ float frcp(float x) { return __builtin_amdgcn_rcpf(x); }
__device__ __forceinline__ float fsig(float x) { return frcp(1.f + fexp(-x)); }
__device__ __forceinline__ float fbce(float x, float y) {
  float t = hw_exp2(-fabsf(x) * L2E);
  return fmaxf(x, 0.f) - x * y + LN2 * hw_log2(1.f + t);
}
__device__ __forceinline__ void anchor_geom(int a, int& hw, int& lw, float& st) {
  if (a < 16384)      { hw = a;         lw = 7; st = 8.f;  }
  else if (a < 20480) { hw = a - 16384; lw = 6; st = 16.f; }
  else                { hw = a - 20480; lw = 5; st = 32.f; }
}

// ---- register bitonic merges for truncated top/bottom-10 lists ----
// a,b: sorted 10-lists (implicit pads at [10..15]). Truncate-to-10 after each
// merge is exact: an element outside a subset's top-10 is never in a
// superset's top-10. First stage = valley CE of [A ; rev(B)] keeping top half;
// then a 4-stage 16-element bitonic merge. All indices compile-time constant.
__device__ __forceinline__ void merge_desc(float* a, const float* b) {
  float m[16];
  m[0] = a[0]; m[1] = a[1]; m[2] = a[2]; m[3] = a[3]; m[4] = a[4]; m[5] = a[5];
  m[6] = fmaxf(a[6], b[9]); m[7] = fmaxf(a[7], b[8]);
  m[8] = fmaxf(a[8], b[7]); m[9] = fmaxf(a[9], b[6]);
  m[10] = b[5]; m[11] = b[4]; m[12] = b[3]; m[13] = b[2]; m[14] = b[1]; m[15] = b[0];
#pragma unroll
  for (int s = 8; s >= 1; s >>= 1) {
#pragma unroll
    for (int i = 0; i < 16; ++i) {
      if (!(i & s)) {
        float hi = fmaxf(m[i], m[i + s]);
        float lo = fminf(m[i], m[i + s]);
        m[i] = hi; m[i + s] = lo;
      }
    }
  }
#pragma unroll
  for (int j = 0; j < 10; ++j) a[j] = m[j];
}

__device__ __forceinline__ void merge_asc(float* ac, int* ai,
                                          const float* bc, const int* bi) {
  float mc[16]; int mi[16];
#pragma unroll
  for (int i = 0; i < 6; ++i) { mc[i] = ac[i]; mi[i] = ai[i]; }
#pragma unroll
  for (int i = 6; i < 10; ++i) {
    float c2 = bc[15 - i]; int i2 = bi[15 - i];
    bool ta = (ac[i] < c2) || (ac[i] == c2 && ai[i] < i2);
    mc[i] = ta ? ac[i] : c2; mi[i] = ta ? ai[i] : i2;
  }
  mc[10] = bc[5]; mi[10] = bi[5]; mc[11] = bc[4]; mi[11] = bi[4];
  mc[12] = bc[3]; mi[12] = bi[3]; mc[13] = bc[2]; mi[13] = bi[2];
  mc[14] = bc[1]; mi[14] = bi[1]; mc[15] = bc[0]; mi[15] = bi[0];
#pragma unroll
  for (int s = 8; s >= 1; s >>= 1) {
#pragma unroll
    for (int i = 0; i < 16; ++i) {
      if (!(i & s)) {
        float cA = mc[i], cB = mc[i + s];
        int   iA = mi[i], iB = mi[i + s];
        bool ta = (cB < cA) || (cB == cA && iB < iA);   // partner smaller?
        mc[i]     = ta ? cB : cA; mi[i]     = ta ? iB : iA;
        mc[i + s] = ta ? cA : cB; mi[i + s] = ta ? iA : iB;
      }
    }
  }
#pragma unroll
  for (int j = 0; j < 10; ++j) { ac[j] = mc[j]; ai[j] = mi[j]; }
}

// -------- fused decode + cost/iou/cand: per-(b,a) thread loops 20 gts --------
__global__ __launch_bounds__(256) void k_cost(
    const float* __restrict__ p3, const float* __restrict__ p4,
    const float* __restrict__ p5, const float* __restrict__ labels,
    float* __restrict__ dec, float* __restrict__ ious,
    float* __restrict__ cost, unsigned char* __restrict__ cand) {
  __shared__ float gt[NG][5];
  int tid = threadIdx.x, b = blockIdx.y;
  if (tid < NG * 5) ((float*)gt)[tid] = labels[b * NG * 5 + tid];
  __syncthreads();
  int a = blockIdx.x * 256 + tid;

  // ---- inline decode ----
  int hw, lw; float st;
  anchor_geom(a, hw, lw, st);
  const float* src; int HW;
  if (a < 16384)      { src = p3; HW = 16384; }
  else if (a < 20480) { src = p4; HW = 4096;  }
  else                { src = p5; HW = 1024;  }
  int x = hw & ((1 << lw) - 1), y = hw >> lw;
  const float* c0 = src + (size_t)b * 8 * HW + hw;
  float o0 = c0[0];
  float o1 = c0[(size_t)HW];
  float o2 = c0[(size_t)2 * HW];
  float o3 = c0[(size_t)3 * HW];
  float o4 = c0[(size_t)4 * HW];
  float o5 = c0[(size_t)5 * HW];
  float o6 = c0[(size_t)6 * HW];
  float o7 = c0[(size_t)7 * HW];
  float px = (o0 + (float)x) * st, py = (o1 + (float)y) * st;
  float pw = fexp(o2) * st,        ph = fexp(o3) * st;
  {
    float4* dst = (float4*)(dec + ((size_t)b * A_TOT + a) * 8);
    dst[0] = make_float4(px, py, pw, ph);
    dst[1] = make_float4(o4, o5, o6, o7);
  }

  float xc = ((float)x + 0.5f) * st, yc = ((float)y + 0.5f) * st;

  float so = fsig(o4);
  float cc0, cc1, cc2, S;
  {
    float q0 = sqrtf(fsig(o5) * so);
    float q1 = sqrtf(fsig(o6) * so);
    float q2 = sqrtf(fsig(o7) * so);
    float lg0 = flog(q0 + 1e-8f), lg1 = flog(q1 + 1e-8f), lg2 = flog(q2 + 1e-8f);
    float m0 = flog(1.f - q0 + 1e-8f), m1 = flog(1.f - q1 + 1e-8f), m2 = flog(1.f - q2 + 1e-8f);
    S = m0 + m1 + m2;
    cc0 = lg0 - m0; cc1 = lg1 - m1; cc2 = lg2 - m2;
  }

  float iouv[NG];
  unsigned bothMask = 0;
  bool anyBox = false, anyCtr = false;
  float hpw = pw * 0.5f, hph = ph * 0.5f;
  float plx = px - hpw, prx = px + hpw, pty = py - hph, pby = py + hph;
  float parea = pw * ph;
  float r = 2.5f * st;

#pragma unroll
  for (int g = 0; g < NG; ++g) {
    float gx = gt[g][0], gy = gt[g][1], gw = gt[g][2], gh = gt[g][3];
    float hgw = gw * 0.5f, hgh = gh * 0.5f;
    float glx = gx - hgw, grx = gx + hgw, gty = gy - hgh, gby = gy + hgh;
    bool ib = (xc > glx) && (xc < grx) && (yc > gty) && (yc < gby);
    bool ic = (xc > gx - r) && (xc < gx + r) && (yc > gy - r) && (yc < gy + r);
    anyBox |= ib; anyCtr |= ic;
    if (ib && ic) bothMask |= (1u << g);
    float tlx = fmaxf(glx, plx), brx = fminf(grx, prx);
    float tly = fmaxf(gty, pty), bry = fminf(gby, pby);
    float en = ((tlx < brx) && (tly < bry)) ? 1.f : 0.f;
    float ai = (brx - tlx) * (bry - tly) * en;
    float au = gw * gh + parea - ai;
    iouv[g] = ai / (au + 1e-16f);
  }
  bool cd = anyBox || anyCtr;
  cand[(size_t)b * A_TOT + a] = cd ? 1 : 0;

#pragma unroll
  for (int g = 0; g < NG; ++g) {
    float iv = cd ? iouv[g] : 0.f;
    int cg = (int)gt[g][4];
    float ccg = (cg == 0) ? cc0 : ((cg == 1) ? cc1 : cc2);
    float c = -(ccg + S) - 3.f * flog(iv + 1e-8f) +
              (((bothMask >> g) & 1u) ? 0.f : 100000.f);
    size_t idx = ((size_t)(b * NG + g)) * A_TOT + a;
    ious[idx] = iv;
    cost[idx] = cd ? c : 1e9f;
  }
}

// -------- per-(b,g,chunk): partial top-10 ious + bottom-10 (cost,idx) --------
// 1 wave per block; register bitonic + shfl_xor butterfly; zero LDS/barriers.
// The d-loop is deliberately NOT unrolled (#pragma unroll 1): each merge
// network inlines exactly once (6x less code than full unroll — the R6
// full-unroll version appeared to hang the backend compiler).
__global__ __launch_bounds__(64) void k_topk_part(
    const float* __restrict__ ious, const float* __restrict__ cost,
    float* __restrict__ pV, float* __restrict__ pC, int* __restrict__ pI) {
  int s = blockIdx.x, g = blockIdx.y, b = blockIdx.z;
  int lane = threadIdx.x;
  int row = b * NG + g;
  int lo = s * CHUNK;
  const float4* iou4 = (const float4*)(ious + (size_t)row * A_TOT + lo);
  const float4* cst4 = (const float4*)(cost + (size_t)row * A_TOT + lo);
  constexpr int NG4 = CHUNK / 4;   // 336 float4 groups per chunk

  float tv[10];
  float tc[10]; int ti[10];
#pragma unroll
  for (int j = 0; j < 10; ++j) { tv[j] = -1e30f; tc[j] = FLT_MAX; ti[j] = 0x7fffffff; }

  auto insV = [&](float v) {
    if (v > tv[9]) {
#pragma unroll
      for (int j = 0; j < 10; ++j)
        if (v > tv[j]) { float t = tv[j]; tv[j] = v; v = t; }
    }
  };
  auto insC = [&](float c, int ii) {
    if ((c < tc[9]) || (c == tc[9] && ii < ti[9])) {
#pragma unroll
      for (int j = 0; j < 10; ++j) {
        bool lt = (c < tc[j]) || (c == tc[j] && ii < ti[j]);
        if (lt) {
          float t = tc[j]; tc[j] = c; c = t;
          int t2 = ti[j]; ti[j] = ii; ii = t2;
        }
      }
    }
  };

#pragma unroll 1
  for (int grp = lane; grp < NG4; grp += 64) {
    float4 v4 = iou4[grp];
    float4 c4 = cst4[grp];
    int base = lo + grp * 4;
    insV(v4.x); insV(v4.y); insV(v4.z); insV(v4.w);
    insC(c4.x, base); insC(c4.y, base + 1); insC(c4.z, base + 2); insC(c4.w, base + 3);
  }

  // wave-level butterfly: runtime-distance loops, body inlined once each
#pragma unroll 1
  for (int d = 1; d < 64; d <<= 1) {
    float bv[10];
#pragma unroll
    for (int j = 0; j < 10; ++j) bv[j] = __shfl_xor(tv[j], d, 64);
    merge_desc(tv, bv);
  }
#pragma unroll 1
  for (int d = 1; d < 64; d <<= 1) {
    float bc[10]; int bi[10];
#pragma unroll
    for (int j = 0; j < 10; ++j) {
      bc[j] = __shfl_xor(tc[j], d, 64);
      bi[j] = __shfl_xor(ti[j], d, 64);
    }
    merge_asc(tc, ti, bc, bi);
  }

  if (lane == 0) {
    size_t base = ((size_t)row * SPLIT + s) * 10;
#pragma unroll
    for (int j = 0; j < 10; ++j) {
      pV[base + j] = tv[j];
      pC[base + j] = tc[j];
      pI[base + j] = ti[j];
    }
  }
}

// -------- per-(b,g): merge 16x10 partials -> dyn_k + threshold (cost,idx) --------
__global__ __launch_bounds__(192) void k_topk_merge(
    const float* __restrict__ pV, const float* __restrict__ pC,
    const int* __restrict__ pI, float* __restrict__ thrC, int* __restrict__ thrI) {
  int g = blockIdx.x, b = blockIdx.y, tid = threadIdx.x;
  int row = b * NG + g;
  constexpr int NC = SPLIT * 10;   // 160 candidates
  __shared__ float sV[NC], sC[NC];
  __shared__ int   sI[NC];
  __shared__ float slot[10];
  __shared__ int kS;

  if (tid < NC) {
    size_t base = (size_t)row * NC + tid;
    sV[tid] = pV[base];
    sC[tid] = pC[base];
    sI[tid] = pI[base];
  }
  __syncthreads();

  float myV = 0.f, myC = 0.f; int myI = 0, rankV = 0;
  if (tid < NC) {
    myV = sV[tid]; myC = sC[tid]; myI = sI[tid];
    for (int j = 0; j < NC; ++j) {
      float v = sV[j];
      rankV += ((v > myV) || (v == myV && j < tid)) ? 1 : 0;
    }
  }
  if (tid < NC && rankV < 10) slot[rankV] = myV;   // ranks 0..9 all exist
  __syncthreads();
  if (tid == 0) {
    float sum = 0.f;
#pragma unroll
    for (int j = 0; j < 10; ++j) sum += slot[j];
    int k = (int)sum; if (k < 1) k = 1;            // dyn_k in [1,10]
    kS = k;
  }
  __syncthreads();
  if (tid < NC) {
    int rankC = 0;
    for (int j = 0; j < NC; ++j) {
      float c = sC[j];
      rankC += ((c < myC) || (c == myC && sI[j] < myI)) ? 1 : 0;
    }
    if (rankC == kS - 1) { thrC[row] = myC; thrI[row] = myI; }
  }
}

// -------- matching resolution + detection loss partials --------
__global__ __launch_bounds__(256) void k_match(
    const float* __restrict__ dec, const float* __restrict__ labels,
    const float* __restrict__ ious, const float* __restrict__ cost,
    const unsigned char* __restrict__ cand,
    const float* __restrict__ thrC, const int* __restrict__ thrI,
    float* __restrict__ pm) {
  __shared__ float gt[NG][5];
  __shared__ float tC[NG];
  __shared__ int   tI[NG];
  int tid = threadIdx.x, b = blockIdx.y;
  if (tid < NG * 5) ((float*)gt)[tid] = labels[b * NG * 5 + tid];
  if (tid >= 128 && tid < 128 + NG) tC[tid - 128] = thrC[b * NG + tid - 128];
  if (tid >= 160 && tid < 160 + NG) tI[tid - 160] = thrI[b * NG + tid - 160];
  __syncthreads();
  int a = blockIdx.x * 256 + tid;

  bool cd = cand[(size_t)b * A_TOT + a] != 0;
  int cnt = 0, firstg = -1, gmin = 0;
  float minc = FLT_MAX, pisum = 0.f, iou_gmin = 0.f;
#pragma unroll
  for (int g = 0; g < NG; ++g) {
    size_t idx = ((size_t)(b * NG + g)) * A_TOT + a;
    float c = cost[idx];
    float iv = ious[idx];
    if (c < minc) { minc = c; gmin = g; iou_gmin = iv; }   // first-argmin
    bool m = cd && ((c < tC[g]) || (c == tC[g] && a <= tI[g]));
    if (m) { cnt++; if (firstg < 0) firstg = g; pisum += iv; }
  }
  if (cnt > 1) { firstg = gmin; pisum = iou_gmin; }  // multi -> best only
  bool fg = cnt > 0;

  const float4* dp = (const float4*)(dec + ((size_t)b * A_TOT + a) * 8);
  float4 d0 = dp[0], d1 = dp[1];
  float l_obj = fbce(d1.x, fg ? 1.f : 0.f);
  float l_iou = 0.f, l_cls = 0.f, nfg = fg ? 1.f : 0.f;
  if (fg) {
    float gx = gt[firstg][0], gy = gt[firstg][1];
    float gw = gt[firstg][2], gh = gt[firstg][3];
    int cg = (int)gt[firstg][4];
    float px = d0.x, py = d0.y, pw = d0.z, ph = d0.w;
    float tlx = fmaxf(px - pw * 0.5f, gx - gw * 0.5f);
    float brx = fminf(px + pw * 0.5f, gx + gw * 0.5f);
    float tly = fmaxf(py - ph * 0.5f, gy - gh * 0.5f);
    float bry = fminf(py + ph * 0.5f, gy + gh * 0.5f);
    float en = ((tlx < brx) && (tly < bry)) ? 1.f : 0.f;
    float ai = (brx - tlx) * (bry - tly) * en;
    float au = pw * ph + gw * gh - ai;
    float iou = ai / (au + 1e-16f);
    l_iou = 1.f - iou * iou;
    l_cls  = fbce(d1.y, (cg == 0) ? pisum : 0.f);
    l_cls += fbce(d1.z, (cg == 1) ? pisum : 0.f);
    l_cls += fbce(d1.w, (cg == 2) ? pisum : 0.f);
  }

  __shared__ float scr[4][4];
  float vals[4] = { nfg, l_iou, l_obj, l_cls };
#pragma unroll
  for (int k = 0; k < 4; ++k) {
    float v = vals[k];
#pragma unroll
    for (int off = 32; off > 0; off >>= 1) v += __shfl_down(v, off, 64);
    if ((tid & 63) == 0) scr[tid >> 6][k] = v;
  }
  __syncthreads();
  if (tid == 0) {
    int bf = blockIdx.y * gridDim.x + blockIdx.x;
#pragma unroll
    for (int k = 0; k < 4; ++k)
      pm[(size_t)bf * 4 + k] = scr[0][k] + scr[1][k] + scr[2][k] + scr[3][k];
  }
}

// -------- mask loss: fused softmax CE + dice stats (HW-trans version) --------
__global__ __launch_bounds__(256) void k_mask(
    const float* __restrict__ mi, const int* __restrict__ ml,
    float* __restrict__ pk) {
  int tid = threadIdx.x;
  int blk = blockIdx.x;
  int b  = blk >> 8;                 // 256 blocks per batch image
  int g0 = (blk & 255) << 10;        // float4-group offset within image
  const float* base0 = mi + (size_t)b * 3 * HW_M + (size_t)g0 * 4;
  const int*   lbase = ml + ((size_t)b << 20) + (size_t)g0 * 4;

  float4 x0[4], x1[4], x2[4]; int4 lb[4];
#pragma unroll
  for (int u = 0; u < 4; ++u) {
    size_t off = (size_t)(tid + u * 256) * 4;
    x0[u] = *(const float4*)(base0 + off);
    x1[u] = *(const float4*)(base0 + HW_M + off);
    x2[u] = *(const float4*)(base0 + 2 * HW_M + off);
    lb[u] = *(const int4*)(lbase + off);
  }

  float ce = 0.f, tp0 = 0, tp1 = 0, tp2 = 0;
  float ss0 = 0, ss1 = 0;            // ss2 derived at the end
  float c0 = 0, c1 = 0;              // c2 derived at the end

  auto proc = [&](float v0, float v1, float v2, int l) {
    float e0 = hw_exp2(v0 * L2E);
    float e1 = hw_exp2(v1 * L2E);
    float e2 = hw_exp2(v2 * L2E);
    float sum = e0 + e1 + e2;
    float inv = __builtin_amdgcn_rcpf(sum);
    float lse = hw_log2(sum) * LN2;
    float s0 = e0 * inv, s1 = e1 * inv;
    ss0 += s0; ss1 += s1;
    bool l0 = (l == 0), l1 = (l == 1);
    float vl = l0 ? v0 : (l1 ? v1 : v2);
    float el = l0 ? e0 : (l1 ? e1 : e2);
    float sl = el * inv;
    ce += vl - lse;
    tp0 += l0 ? sl : 0.f;
    tp1 += l1 ? sl : 0.f;
    tp2 += (!l0 && !l1) ? sl : 0.f;
    c0 += l0 ? 1.f : 0.f;
    c1 += l1 ? 1.f : 0.f;
  };

#pragma unroll
  for (int u = 0; u < 4; ++u) {
    proc(x0[u].x, x1[u].x, x2[u].x, lb[u].x);
    proc(x0[u].y, x1[u].y, x2[u].y, lb[u].y);
    proc(x0[u].z, x1[u].z, x2[u].z, lb[u].z);
    proc(x0[u].w, x1[u].w, x2[u].w, lb[u].w);
  }
  float ss2 = 16.f - ss0 - ss1;
  float c2 = 16.f - c0 - c1;

  __shared__ float scr[4][10];
  float vals[10] = { ce, tp0, tp1, tp2, ss0, ss1, ss2, c0, c1, c2 };
#pragma unroll
  for (int k = 0; k < 10; ++k) {
    float v = vals[k];
#pragma unroll
    for (int off = 32; off > 0; off >>= 1) v += __shfl_down(v, off, 64);
    if ((tid & 63) == 0) scr[tid >> 6][k] = v;
  }
  __syncthreads();
  if (tid == 0) {
#pragma unroll
    for (int k = 0; k < 10; ++k)
      pk[(size_t)blk * 10 + k] = scr[0][k] + scr[1][k] + scr[2][k] + scr[3][k];
  }
}

// -------- final reduce + output --------
__device__ __forceinline__ float bsum256(float v, float* scr) {
#pragma unroll
  for (int off = 32; off > 0; off >>= 1) v += __shfl_down(v, off, 64);
  __syncthreads();
  if ((threadIdx.x & 63) == 0) scr[threadIdx.x >> 6] = v;
  __syncthreads();
  return scr[0] + scr[1] + scr[2] + scr[3];
}

__global__ __launch_bounds__(256) void k_final(
    const float* __restrict__ pm, const float* __restrict__ pk,
    float* __restrict__ out) {
  __shared__ float scr[4];
  int tid = threadIdx.x;
  float t0 = 0, t1 = 0, t2 = 0, t3 = 0;
  for (int r = tid; r < 672; r += 256) {
    t0 += pm[(size_t)r * 4 + 0];
    t1 += pm[(size_t)r * 4 + 1];
    t2 += pm[(size_t)r * 4 + 2];
    t3 += pm[(size_t)r * 4 + 3];
  }
  float u[10] = {0,0,0,0,0,0,0,0,0,0};
  for (int r = tid; r < MBLK; r += 256) {
#pragma unroll
    for (int k = 0; k < 10; ++k) u[k] += pk[(size_t)r * 10 + k];
  }
  float S_nfg = bsum256(t0, scr);
  float S_iou = bsum256(t1, scr);
  float S_obj = bsum256(t2, scr);
  float S_cls = bsum256(t3, scr);
  float S_ce  = bsum256(u[0], scr);
  float S_tp0 = bsum256(u[1], scr);
  float S_tp1 = bsum256(u[2], scr);
  float S_tp2 = bsum256(u[3], scr);
  float S_ss0 = bsum256(u[4], scr);
  float S_ss1 = bsum256(u[5], scr);
  float S_ss2 = bsum256(u[6], scr);
  float S_c0  = bsum256(u[7], scr);
  float S_c1  = bsum256(u[8], scr);
  float S_c2  = bsum256(u[9], scr);

  if (tid == 0) {
    float nfg = fmaxf(S_nfg, 1.f);
    float o1 = 5.f * S_iou / nfg;
    float o2 = S_obj / nfg;
    float o3 = S_cls / nfg;
    float ce = -S_ce / (float)((long long)NB << 20);
    float tps[3] = { S_tp0, S_tp1, S_tp2 };
    float sss[3] = { S_ss0, S_ss1, S_ss2 };
    float cns[3] = { S_c0, S_c1, S_c2 };
    float ds = 0.f;
#pragma unroll
    for (int c = 0; c < 3; ++c) {
      float tp = tps[c];
      float fp = sss[c] - tp;
      float fn = cns[c] - tp;
      ds += (2.f * tp + 1e-5f) / (2.f * tp + fn + fp + 1e-5f);
    }
    float dice = 1.f - ds / 3.f;
    float o4 = ce + dice;
    out[0] = o1 + o2 + o3 + o4;
    out[1] = o1;
    out[2] = o2;
    out[3] = o3;
    out[4] = o4;
    out[5] = 0.f;
  }
}

extern "C" void kernel_launch(void* const* d_in, const int* in_sizes, int n_in,
                              void* d_out, int out_size, void* d_ws, size_t ws_size,
                              hipStream_t stream) {
  const float* p3     = (const float*)d_in[0];
  const float* p4     = (const float*)d_in[1];
  const float* p5     = (const float*)d_in[2];
  const float* mi     = (const float*)d_in[3];
  const float* labels = (const float*)d_in[4];
  // d_in[5] input_images: unused by the loss
  const int*   ml     = (const int*)d_in[6];
  // d_in[7] now_epoch: unused

  float* ws   = (float*)d_ws;
  float* dec  = ws + OFF_DEC;
  float* ious = ws + OFF_IOUS;
  float* cost = ws + OFF_COST;
  float* thrC = ws + OFF_THRC;
  int*   thrI = (int*)(ws + OFF_THRI);
  unsigned char* cand = (unsigned char*)(ws + OFF_CAND);
  float* pm   = ws + OFF_PM;
  float* pk   = ws + OFF_PK;
  float* pV   = ws + OFF_PV;
  float* pC   = ws + OFF_PC;
  int*   pI   = (int*)(ws + OFF_PI);
  float* out  = (float*)d_out;

  dim3 gA(A_TOT / 256, NB);   // 21504 = 84*256 exactly
  k_cost<<<gA, 256, 0, stream>>>(p3, p4, p5, labels, dec, ious, cost, cand);
  k_topk_part<<<dim3(SPLIT, NG, NB), 64, 0, stream>>>(ious, cost, pV, pC, pI);
  k_topk_merge<<<dim3(NG, NB), 192, 0, stream>>>(pV, pC, pI, thrC, thrI);
  k_match<<<gA, 256, 0, stream>>>(dec, labels, ious, cost, cand, thrC, thrI, pm);
  k_mask<<<MBLK, 256, 0, stream>>>(mi, ml, pk);
  k_final<<<1, 256, 0, stream>>>(pm, pk, out);
}

// Round 8
// 90.894 us; speedup vs baseline: 1.7685x; 1.1492x over previous
//
#include <hip/hip_runtime.h>
#include <cfloat>

// ---- problem constants (fixed by setup_inputs) ----
constexpr int A_TOT = 21504;      // 128^2 + 64^2 + 32^2
constexpr int NB    = 8;
constexpr int NG    = 20;
constexpr int HW_M  = 1 << 20;    // 1024*1024
constexpr int SPLIT = 16;         // chunks per (b,g) row for top-k
constexpr int CHUNK = A_TOT / SPLIT;   // 1344
constexpr int MBLK  = 2048;       // mask virtual blocks (256 per batch image)
constexpr int MSLC  = MBLK / 4;   // 512: mask slice appended to each det kernel

constexpr float L2E = 1.44269504088896340736f;
constexpr float LN2 = 0.69314718055994530942f;

// ---- workspace layout (float offsets) ----
constexpr size_t OFF_DEC  = 0;
constexpr size_t SZ_DEC   = (size_t)NB * A_TOT * 8;            // 1,376,256
constexpr size_t OFF_IOUS = OFF_DEC + SZ_DEC;
constexpr size_t SZ_GA    = (size_t)NB * NG * A_TOT;           // 3,440,640
constexpr size_t OFF_COST = OFF_IOUS + SZ_GA;
constexpr size_t OFF_THRC = OFF_COST + SZ_GA;                  // NB*NG floats
constexpr size_t OFF_THRI = OFF_THRC + NB * NG;                // NB*NG ints
constexpr size_t OFF_CAND = OFF_THRI + NB * NG;                // NB*A_TOT bytes
constexpr size_t OFF_PM   = OFF_CAND + (NB * A_TOT) / 4;       // 672*4 floats
constexpr size_t OFF_PK   = OFF_PM + 672 * 4;                  // MBLK*10 floats
constexpr size_t OFF_PV   = OFF_PK + (size_t)MBLK * 10;        // part iou vals
constexpr size_t SZ_PART  = (size_t)NB * NG * SPLIT * 10;      // 25,600
constexpr size_t OFF_PC   = OFF_PV + SZ_PART;                  // part costs
constexpr size_t OFF_PI   = OFF_PC + SZ_PART;                  // part idx (int)

// ---- fast transcendentals: single HW instruction each (~1 ulp) ----
// NOTE: __builtin_amdgcn_logf IS v_log_f32 (log2) on ROCm/clang.
__device__ __forceinline__ float hw_exp2(float x) { return __builtin_amdgcn_exp2f(x); }
__device__ __forceinline__ float hw_log2(float x) { return __builtin_amdgcn_logf(x); }
__device__ __forceinline__ float fexp(float x) { return hw_exp2(x * L2E); }   // e^x
__device__ __forceinline__ float flog(float x) { return hw_log2(x) * LN2; }   // ln(x)
__device__ __forceinline__ float frcp(float x) { return __builtin_amdgcn_rcpf(x); }
__device__ __forceinline__ float fsig(float x) { return frcp(1.f + fexp(-x)); }
__device__ __forceinline__ float fbce(float x, float y) {
  float t = hw_exp2(-fabsf(x) * L2E);
  return fmaxf(x, 0.f) - x * y + LN2 * hw_log2(1.f + t);
}
__device__ __forceinline__ void anchor_geom(int a, int& hw, int& lw, float& st) {
  if (a < 16384)      { hw = a;         lw = 7; st = 8.f;  }
  else if (a < 20480) { hw = a - 16384; lw = 6; st = 16.f; }
  else                { hw = a - 20480; lw = 5; st = 32.f; }
}

// ---- register bitonic merges for truncated top/bottom-10 lists ----
__device__ __forceinline__ void merge_desc(float* a, const float* b) {
  float m[16];
  m[0] = a[0]; m[1] = a[1]; m[2] = a[2]; m[3] = a[3]; m[4] = a[4]; m[5] = a[5];
  m[6] = fmaxf(a[6], b[9]); m[7] = fmaxf(a[7], b[8]);
  m[8] = fmaxf(a[8], b[7]); m[9] = fmaxf(a[9], b[6]);
  m[10] = b[5]; m[11] = b[4]; m[12] = b[3]; m[13] = b[2]; m[14] = b[1]; m[15] = b[0];
#pragma unroll
  for (int s = 8; s >= 1; s >>= 1) {
#pragma unroll
    for (int i = 0; i < 16; ++i) {
      if (!(i & s)) {
        float hi = fmaxf(m[i], m[i + s]);
        float lo = fminf(m[i], m[i + s]);
        m[i] = hi; m[i + s] = lo;
      }
    }
  }
#pragma unroll
  for (int j = 0; j < 10; ++j) a[j] = m[j];
}

__device__ __forceinline__ void merge_asc(float* ac, int* ai,
                                          const float* bc, const int* bi) {
  float mc[16]; int mi[16];
#pragma unroll
  for (int i = 0; i < 6; ++i) { mc[i] = ac[i]; mi[i] = ai[i]; }
#pragma unroll
  for (int i = 6; i < 10; ++i) {
    float c2 = bc[15 - i]; int i2 = bi[15 - i];
    bool ta = (ac[i] < c2) || (ac[i] == c2 && ai[i] < i2);
    mc[i] = ta ? ac[i] : c2; mi[i] = ta ? ai[i] : i2;
  }
  mc[10] = bc[5]; mi[10] = bi[5]; mc[11] = bc[4]; mi[11] = bi[4];
  mc[12] = bc[3]; mi[12] = bi[3]; mc[13] = bc[2]; mi[13] = bi[2];
  mc[14] = bc[1]; mi[14] = bi[1]; mc[15] = bc[0]; mi[15] = bi[0];
#pragma unroll
  for (int s = 8; s >= 1; s >>= 1) {
#pragma unroll
    for (int i = 0; i < 16; ++i) {
      if (!(i & s)) {
        float cA = mc[i], cB = mc[i + s];
        int   iA = mi[i], iB = mi[i + s];
        bool ta = (cB < cA) || (cB == cA && iB < iA);
        mc[i]     = ta ? cB : cA; mi[i]     = ta ? iB : iA;
        mc[i + s] = ta ? cA : cB; mi[i + s] = ta ? iA : iB;
      }
    }
  }
#pragma unroll
  for (int j = 0; j < 10; ++j) { ac[j] = mc[j]; ai[j] = mi[j]; }
}

// ---- mask slice: one virtual block (4096 pixels) of the seg CE+dice sums ----
// Called by ALL 256 threads of a block (contains barriers).
__device__ __forceinline__ void mask_block(int vblk,
    const float* __restrict__ mi, const int* __restrict__ ml,
    float* __restrict__ pk, int tid) {
  int b  = vblk >> 8;
  int g0 = (vblk & 255) << 10;
  const float* base0 = mi + (size_t)b * 3 * HW_M + (size_t)g0 * 4;
  const int*   lbase = ml + ((size_t)b << 20) + (size_t)g0 * 4;

  float4 x0[4], x1[4], x2[4]; int4 lb[4];
#pragma unroll
  for (int u = 0; u < 4; ++u) {
    size_t off = (size_t)(tid + u * 256) * 4;
    x0[u] = *(const float4*)(base0 + off);
    x1[u] = *(const float4*)(base0 + HW_M + off);
    x2[u] = *(const float4*)(base0 + 2 * HW_M + off);
    lb[u] = *(const int4*)(lbase + off);
  }

  float ce = 0.f, tp0 = 0, tp1 = 0, tp2 = 0;
  float ss0 = 0, ss1 = 0, c0 = 0, c1 = 0;

  auto proc = [&](float v0, float v1, float v2, int l) {
    float e0 = hw_exp2(v0 * L2E);
    float e1 = hw_exp2(v1 * L2E);
    float e2 = hw_exp2(v2 * L2E);
    float sum = e0 + e1 + e2;
    float inv = __builtin_amdgcn_rcpf(sum);
    float lse = hw_log2(sum) * LN2;
    float s0 = e0 * inv, s1 = e1 * inv;
    ss0 += s0; ss1 += s1;
    bool l0 = (l == 0), l1 = (l == 1);
    float vl = l0 ? v0 : (l1 ? v1 : v2);
    float el = l0 ? e0 : (l1 ? e1 : e2);
    float sl = el * inv;
    ce += vl - lse;
    tp0 += l0 ? sl : 0.f;
    tp1 += l1 ? sl : 0.f;
    tp2 += (!l0 && !l1) ? sl : 0.f;
    c0 += l0 ? 1.f : 0.f;
    c1 += l1 ? 1.f : 0.f;
  };

#pragma unroll
  for (int u = 0; u < 4; ++u) {
    proc(x0[u].x, x1[u].x, x2[u].x, lb[u].x);
    proc(x0[u].y, x1[u].y, x2[u].y, lb[u].y);
    proc(x0[u].z, x1[u].z, x2[u].z, lb[u].z);
    proc(x0[u].w, x1[u].w, x2[u].w, lb[u].w);
  }
  float ss2 = 16.f - ss0 - ss1;
  float c2 = 16.f - c0 - c1;

  __shared__ float scr[4][10];
  float vals[10] = { ce, tp0, tp1, tp2, ss0, ss1, ss2, c0, c1, c2 };
#pragma unroll
  for (int k = 0; k < 10; ++k) {
    float v = vals[k];
#pragma unroll
    for (int off = 32; off > 0; off >>= 1) v += __shfl_down(v, off, 64);
    if ((tid & 63) == 0) scr[tid >> 6][k] = v;
  }
  __syncthreads();
  if (tid == 0) {
#pragma unroll
    for (int k = 0; k < 10; ++k)
      pk[(size_t)vblk * 10 + k] = scr[0][k] + scr[1][k] + scr[2][k] + scr[3][k];
  }
}

// ======== K1: fused decode+cost (672 blocks) | mask slice 0 (512) ========
__global__ __launch_bounds__(256) void k_cost_mask(
    const float* __restrict__ p3, const float* __restrict__ p4,
    const float* __restrict__ p5, const float* __restrict__ labels,
    float* __restrict__ dec, float* __restrict__ ious,
    float* __restrict__ cost, unsigned char* __restrict__ cand,
    const float* __restrict__ mi, const int* __restrict__ ml,
    float* __restrict__ pk) {
  int bi = blockIdx.x, tid = threadIdx.x;
  if (bi >= 672) { mask_block(bi - 672, mi, ml, pk, tid); return; }
  int b = bi / 84, cx = bi - b * 84;

  __shared__ float gt[NG][5];
  if (tid < NG * 5) ((float*)gt)[tid] = labels[b * NG * 5 + tid];
  __syncthreads();
  int a = cx * 256 + tid;

  int hw, lw; float st;
  anchor_geom(a, hw, lw, st);
  const float* src; int HW;
  if (a < 16384)      { src = p3; HW = 16384; }
  else if (a < 20480) { src = p4; HW = 4096;  }
  else                { src = p5; HW = 1024;  }
  int x = hw & ((1 << lw) - 1), y = hw >> lw;
  const float* c0 = src + (size_t)b * 8 * HW + hw;
  float o0 = c0[0];
  float o1 = c0[(size_t)HW];
  float o2 = c0[(size_t)2 * HW];
  float o3 = c0[(size_t)3 * HW];
  float o4 = c0[(size_t)4 * HW];
  float o5 = c0[(size_t)5 * HW];
  float o6 = c0[(size_t)6 * HW];
  float o7 = c0[(size_t)7 * HW];
  float px = (o0 + (float)x) * st, py = (o1 + (float)y) * st;
  float pw = fexp(o2) * st,        ph = fexp(o3) * st;
  {
    float4* dst = (float4*)(dec + ((size_t)b * A_TOT + a) * 8);
    dst[0] = make_float4(px, py, pw, ph);
    dst[1] = make_float4(o4, o5, o6, o7);
  }

  float xc = ((float)x + 0.5f) * st, yc = ((float)y + 0.5f) * st;

  float so = fsig(o4);
  float cc0, cc1, cc2, S;
  {
    float q0 = sqrtf(fsig(o5) * so);
    float q1 = sqrtf(fsig(o6) * so);
    float q2 = sqrtf(fsig(o7) * so);
    float lg0 = flog(q0 + 1e-8f), lg1 = flog(q1 + 1e-8f), lg2 = flog(q2 + 1e-8f);
    float m0 = flog(1.f - q0 + 1e-8f), m1 = flog(1.f - q1 + 1e-8f), m2 = flog(1.f - q2 + 1e-8f);
    S = m0 + m1 + m2;
    cc0 = lg0 - m0; cc1 = lg1 - m1; cc2 = lg2 - m2;
  }

  float iouv[NG];
  unsigned bothMask = 0;
  bool anyBox = false, anyCtr = false;
  float hpw = pw * 0.5f, hph = ph * 0.5f;
  float plx = px - hpw, prx = px + hpw, pty = py - hph, pby = py + hph;
  float parea = pw * ph;
  float r = 2.5f * st;

#pragma unroll
  for (int g = 0; g < NG; ++g) {
    float gx = gt[g][0], gy = gt[g][1], gw = gt[g][2], gh = gt[g][3];
    float hgw = gw * 0.5f, hgh = gh * 0.5f;
    float glx = gx - hgw, grx = gx + hgw, gty = gy - hgh, gby = gy + hgh;
    bool ib = (xc > glx) && (xc < grx) && (yc > gty) && (yc < gby);
    bool ic = (xc > gx - r) && (xc < gx + r) && (yc > gy - r) && (yc < gy + r);
    anyBox |= ib; anyCtr |= ic;
    if (ib && ic) bothMask |= (1u << g);
    float tlx = fmaxf(glx, plx), brx = fminf(grx, prx);
    float tly = fmaxf(gty, pty), bry = fminf(gby, pby);
    float en = ((tlx < brx) && (tly < bry)) ? 1.f : 0.f;
    float ai = (brx - tlx) * (bry - tly) * en;
    float au = gw * gh + parea - ai;
    iouv[g] = ai / (au + 1e-16f);
  }
  bool cd = anyBox || anyCtr;
  cand[(size_t)b * A_TOT + a] = cd ? 1 : 0;

#pragma unroll
  for (int g = 0; g < NG; ++g) {
    float iv = cd ? iouv[g] : 0.f;
    int cg = (int)gt[g][4];
    float ccg = (cg == 0) ? cc0 : ((cg == 1) ? cc1 : cc2);
    float c = -(ccg + S) - 3.f * flog(iv + 1e-8f) +
              (((bothMask >> g) & 1u) ? 0.f : 100000.f);
    size_t idx = ((size_t)(b * NG + g)) * A_TOT + a;
    ious[idx] = iv;
    cost[idx] = cd ? c : 1e9f;
  }
}

// ======== K2: topk partials (640 blocks = 2560 waves) | mask slice 1 ========
__global__ __launch_bounds__(256) void k_topk_mask(
    const float* __restrict__ ious, const float* __restrict__ cost,
    float* __restrict__ pV, float* __restrict__ pC, int* __restrict__ pI,
    const float* __restrict__ mi, const int* __restrict__ ml,
    float* __restrict__ pk) {
  int bi = blockIdx.x, tid = threadIdx.x;
  if (bi >= 640) { mask_block(MSLC + (bi - 640), mi, ml, pk, tid); return; }

  int w = tid >> 6, lane = tid & 63;
  int t = bi * 4 + w;                       // wave task in [0, 2560)
  int b = t / (NG * SPLIT);
  int rem = t - b * (NG * SPLIT);
  int g = rem / SPLIT;
  int s = rem - g * SPLIT;
  int row = b * NG + g;
  int lo = s * CHUNK;
  const float4* iou4 = (const float4*)(ious + (size_t)row * A_TOT + lo);
  const float4* cst4 = (const float4*)(cost + (size_t)row * A_TOT + lo);
  constexpr int NG4 = CHUNK / 4;   // 336

  float tv[10];
  float tc[10]; int ti[10];
#pragma unroll
  for (int j = 0; j < 10; ++j) { tv[j] = -1e30f; tc[j] = FLT_MAX; ti[j] = 0x7fffffff; }

  auto insV = [&](float v) {
    if (v > tv[9]) {
#pragma unroll
      for (int j = 0; j < 10; ++j)
        if (v > tv[j]) { float t2 = tv[j]; tv[j] = v; v = t2; }
    }
  };
  auto insC = [&](float c, int ii) {
    if ((c < tc[9]) || (c == tc[9] && ii < ti[9])) {
#pragma unroll
      for (int j = 0; j < 10; ++j) {
        bool lt = (c < tc[j]) || (c == tc[j] && ii < ti[j]);
        if (lt) {
          float t2 = tc[j]; tc[j] = c; c = t2;
          int t3 = ti[j]; ti[j] = ii; ii = t3;
        }
      }
    }
  };

#pragma unroll 1
  for (int grp = lane; grp < NG4; grp += 64) {
    float4 v4 = iou4[grp];
    float4 c4 = cst4[grp];
    int base = lo + grp * 4;
    insV(v4.x); insV(v4.y); insV(v4.z); insV(v4.w);
    insC(c4.x, base); insC(c4.y, base + 1); insC(c4.z, base + 2); insC(c4.w, base + 3);
  }

  // wave butterfly (runtime distance: body inlined once — R6 compile lesson)
#pragma unroll 1
  for (int d = 1; d < 64; d <<= 1) {
    float bv[10];
#pragma unroll
    for (int j = 0; j < 10; ++j) bv[j] = __shfl_xor(tv[j], d, 64);
    merge_desc(tv, bv);
  }
#pragma unroll 1
  for (int d = 1; d < 64; d <<= 1) {
    float bc[10]; int bi2[10];
#pragma unroll
    for (int j = 0; j < 10; ++j) {
      bc[j] = __shfl_xor(tc[j], d, 64);
      bi2[j] = __shfl_xor(ti[j], d, 64);
    }
    merge_asc(tc, ti, bc, bi2);
  }

  if (lane == 0) {
    size_t base = ((size_t)row * SPLIT + s) * 10;
#pragma unroll
    for (int j = 0; j < 10; ++j) {
      pV[base + j] = tv[j];
      pC[base + j] = tc[j];
      pI[base + j] = ti[j];
    }
  }
}

// ======== K3: merge partials -> dyn_k + threshold (160) | mask slice 2 ========
__global__ __launch_bounds__(256) void k_merge_mask(
    const float* __restrict__ pV, const float* __restrict__ pC,
    const int* __restrict__ pI, float* __restrict__ thrC, int* __restrict__ thrI,
    const float* __restrict__ mi, const int* __restrict__ ml,
    float* __restrict__ pk) {
  int bi = blockIdx.x, tid = threadIdx.x;
  if (bi >= 160) { mask_block(2 * MSLC + (bi - 160), mi, ml, pk, tid); return; }
  int row = bi;
  constexpr int NC = SPLIT * 10;   // 160 candidates
  __shared__ float sV[NC], sC[NC];
  __shared__ int   sI[NC];
  __shared__ float slot[10];
  __shared__ int kS;

  if (tid < NC) {
    size_t base = (size_t)row * NC + tid;
    sV[tid] = pV[base];
    sC[tid] = pC[base];
    sI[tid] = pI[base];
  }
  __syncthreads();

  float myV = 0.f, myC = 0.f; int myI = 0, rankV = 0;
  if (tid < NC) {
    myV = sV[tid]; myC = sC[tid]; myI = sI[tid];
    for (int j = 0; j < NC; ++j) {
      float v = sV[j];
      rankV += ((v > myV) || (v == myV && j < tid)) ? 1 : 0;
    }
  }
  if (tid < NC && rankV < 10) slot[rankV] = myV;
  __syncthreads();
  if (tid == 0) {
    float sum = 0.f;
#pragma unroll
    for (int j = 0; j < 10; ++j) sum += slot[j];
    int k = (int)sum; if (k < 1) k = 1;            // dyn_k in [1,10]
    kS = k;
  }
  __syncthreads();
  if (tid < NC) {
    int rankC = 0;
    for (int j = 0; j < NC; ++j) {
      float c = sC[j];
      rankC += ((c < myC) || (c == myC && sI[j] < myI)) ? 1 : 0;
    }
    if (rankC == kS - 1) { thrC[row] = myC; thrI[row] = myI; }
  }
}

// ======== K4: match + det losses (672) | mask slice 3 ========
__global__ __launch_bounds__(256) void k_match_mask(
    const float* __restrict__ dec, const float* __restrict__ labels,
    const float* __restrict__ ious, const float* __restrict__ cost,
    const unsigned char* __restrict__ cand,
    const float* __restrict__ thrC, const int* __restrict__ thrI,
    float* __restrict__ pm,
    const float* __restrict__ mi, const int* __restrict__ ml,
    float* __restrict__ pk) {
  int bi = blockIdx.x, tid = threadIdx.x;
  if (bi >= 672) { mask_block(3 * MSLC + (bi - 672), mi, ml, pk, tid); return; }
  int b = bi / 84, cx = bi - b * 84;

  __shared__ float gt[NG][5];
  __shared__ float tC[NG];
  __shared__ int   tI[NG];
  if (tid < NG * 5) ((float*)gt)[tid] = labels[b * NG * 5 + tid];
  if (tid >= 128 && tid < 128 + NG) tC[tid - 128] = thrC[b * NG + tid - 128];
  if (tid >= 160 && tid < 160 + NG) tI[tid - 160] = thrI[b * NG + tid - 160];
  __syncthreads();
  int a = cx * 256 + tid;

  bool cd = cand[(size_t)b * A_TOT + a] != 0;
  int cnt = 0, firstg = -1, gmin = 0;
  float minc = FLT_MAX, pisum = 0.f, iou_gmin = 0.f;
#pragma unroll
  for (int g = 0; g < NG; ++g) {
    size_t idx = ((size_t)(b * NG + g)) * A_TOT + a;
    float c = cost[idx];
    float iv = ious[idx];
    if (c < minc) { minc = c; gmin = g; iou_gmin = iv; }   // first-argmin
    bool m = cd && ((c < tC[g]) || (c == tC[g] && a <= tI[g]));
    if (m) { cnt++; if (firstg < 0) firstg = g; pisum += iv; }
  }
  if (cnt > 1) { firstg = gmin; pisum = iou_gmin; }  // multi -> best only
  bool fg = cnt > 0;

  const float4* dp = (const float4*)(dec + ((size_t)b * A_TOT + a) * 8);
  float4 d0 = dp[0], d1 = dp[1];
  float l_obj = fbce(d1.x, fg ? 1.f : 0.f);
  float l_iou = 0.f, l_cls = 0.f, nfg = fg ? 1.f : 0.f;
  if (fg) {
    float gx = gt[firstg][0], gy = gt[firstg][1];
    float gw = gt[firstg][2], gh = gt[firstg][3];
    int cg = (int)gt[firstg][4];
    float px = d0.x, py = d0.y, pw = d0.z, ph = d0.w;
    float tlx = fmaxf(px - pw * 0.5f, gx - gw * 0.5f);
    float brx = fminf(px + pw * 0.5f, gx + gw * 0.5f);
    float tly = fmaxf(py - ph * 0.5f, gy - gh * 0.5f);
    float bry = fminf(py + ph * 0.5f, gy + gh * 0.5f);
    float en = ((tlx < brx) && (tly < bry)) ? 1.f : 0.f;
    float ai = (brx - tlx) * (bry - tly) * en;
    float au = pw * ph + gw * gh - ai;
    float iou = ai / (au + 1e-16f);
    l_iou = 1.f - iou * iou;
    l_cls  = fbce(d1.y, (cg == 0) ? pisum : 0.f);
    l_cls += fbce(d1.z, (cg == 1) ? pisum : 0.f);
    l_cls += fbce(d1.w, (cg == 2) ? pisum : 0.f);
  }

  __shared__ float scr2[4][4];
  float vals[4] = { nfg, l_iou, l_obj, l_cls };
#pragma unroll
  for (int k = 0; k < 4; ++k) {
    float v = vals[k];
#pragma unroll
    for (int off = 32; off > 0; off >>= 1) v += __shfl_down(v, off, 64);
    if ((tid & 63) == 0) scr2[tid >> 6][k] = v;
  }
  __syncthreads();
  if (tid == 0) {
#pragma unroll
    for (int k = 0; k < 4; ++k)
      pm[(size_t)bi * 4 + k] = scr2[0][k] + scr2[1][k] + scr2[2][k] + scr2[3][k];
  }
}

// -------- final reduce + output --------
__device__ __forceinline__ float bsum256(float v, float* scr) {
#pragma unroll
  for (int off = 32; off > 0; off >>= 1) v += __shfl_down(v, off, 64);
  __syncthreads();
  if ((threadIdx.x & 63) == 0) scr[threadIdx.x >> 6] = v;
  __syncthreads();
  return scr[0] + scr[1] + scr[2] + scr[3];
}

__global__ __launch_bounds__(256) void k_final(
    const float* __restrict__ pm, const float* __restrict__ pk,
    float* __restrict__ out) {
  __shared__ float scr[4];
  int tid = threadIdx.x;
  float t0 = 0, t1 = 0, t2 = 0, t3 = 0;
  for (int r = tid; r < 672; r += 256) {
    t0 += pm[(size_t)r * 4 + 0];
    t1 += pm[(size_t)r * 4 + 1];
    t2 += pm[(size_t)r * 4 + 2];
    t3 += pm[(size_t)r * 4 + 3];
  }
  float u[10] = {0,0,0,0,0,0,0,0,0,0};
  for (int r = tid; r < MBLK; r += 256) {
#pragma unroll
    for (int k = 0; k < 10; ++k) u[k] += pk[(size_t)r * 10 + k];
  }
  float S_nfg = bsum256(t0, scr);
  float S_iou = bsum256(t1, scr);
  float S_obj = bsum256(t2, scr);
  float S_cls = bsum256(t3, scr);
  float S_ce  = bsum256(u[0], scr);
  float S_tp0 = bsum256(u[1], scr);
  float S_tp1 = bsum256(u[2], scr);
  float S_tp2 = bsum256(u[3], scr);
  float S_ss0 = bsum256(u[4], scr);
  float S_ss1 = bsum256(u[5], scr);
  float S_ss2 = bsum256(u[6], scr);
  float S_c0  = bsum256(u[7], scr);
  float S_c1  = bsum256(u[8], scr);
  float S_c2  = bsum256(u[9], scr);

  if (tid == 0) {
    float nfg = fmaxf(S_nfg, 1.f);
    float o1 = 5.f * S_iou / nfg;
    float o2 = S_obj / nfg;
    float o3 = S_cls / nfg;
    float ce = -S_ce / (float)((long long)NB << 20);
    float tps[3] = { S_tp0, S_tp1, S_tp2 };
    float sss[3] = { S_ss0, S_ss1, S_ss2 };
    float cns[3] = { S_c0, S_c1, S_c2 };
    float ds = 0.f;
#pragma unroll
    for (int c = 0; c < 3; ++c) {
      float tp = tps[c];
      float fp = sss[c] - tp;
      float fn = cns[c] - tp;
      ds += (2.f * tp + 1e-5f) / (2.f * tp + fn + fp + 1e-5f);
    }
    float dice = 1.f - ds / 3.f;
    float o4 = ce + dice;
    out[0] = o1 + o2 + o3 + o4;
    out[1] = o1;
    out[2] = o2;
    out[3] = o3;
    out[4] = o4;
    out[5] = 0.f;
  }
}

extern "C" void kernel_launch(void* const* d_in, const int* in_sizes, int n_in,
                              void* d_out, int out_size, void* d_ws, size_t ws_size,
                              hipStream_t stream) {
  const float* p3     = (const float*)d_in[0];
  const float* p4     = (const float*)d_in[1];
  const float* p5     = (const float*)d_in[2];
  const float* mi     = (const float*)d_in[3];
  const float* labels = (const float*)d_in[4];
  // d_in[5] input_images: unused by the loss
  const int*   ml     = (const int*)d_in[6];
  // d_in[7] now_epoch: unused

  float* ws   = (float*)d_ws;
  float* dec  = ws + OFF_DEC;
  float* ious = ws + OFF_IOUS;
  float* cost = ws + OFF_COST;
  float* thrC = ws + OFF_THRC;
  int*   thrI = (int*)(ws + OFF_THRI);
  unsigned char* cand = (unsigned char*)(ws + OFF_CAND);
  float* pm   = ws + OFF_PM;
  float* pk   = ws + OFF_PK;
  float* pV   = ws + OFF_PV;
  float* pC   = ws + OFF_PC;
  int*   pI   = (int*)(ws + OFF_PI);
  float* out  = (float*)d_out;

  // Det work + 1/4 of the mask in each kernel (mask is independent of det;
  // co-scheduling it hides it behind the det critical path).
  k_cost_mask <<<672 + MSLC, 256, 0, stream>>>(p3, p4, p5, labels, dec, ious,
                                               cost, cand, mi, ml, pk);
  k_topk_mask <<<640 + MSLC, 256, 0, stream>>>(ious, cost, pV, pC, pI,
                                               mi, ml, pk);
  k_merge_mask<<<160 + MSLC, 256, 0, stream>>>(pV, pC, pI, thrC, thrI,
                                               mi, ml, pk);
  k_match_mask<<<672 + MSLC, 256, 0, stream>>>(dec, labels, ious, cost, cand,
                                               thrC, thrI, pm, mi, ml, pk);
  k_final<<<1, 256, 0, stream>>>(pm, pk, out);
}